// Round 5
// baseline (448.862 us; speedup 1.0000x reference)
//
#include <hip/hip_runtime.h>
#include <hip/hip_bf16.h>

// Selective SSM (Mamba-style): B=2, L=1024, H=2048, E=2 -> d=4096, S=16, R=128.
// Round 12 (retry; previous bench died on container infra, no kernel verdict):
// phase-split the ring-4 GEMM K-step into 2 phases of 16 MFMA (m201-style
// granularity: 8 phases per K=128). Each phase: af ds_reads -> setprio(1) ->
// 16 MFMA -> setprio(0) -> s_barrier. Creates wave role diversity (some waves
// on LDS pipe while others on MFMA pipe) that the phase-locked 1-phase
// schedule lacked (MfmaUtil 33%). Ring WAR safety unchanged: last ds_read
// still precedes the iteration's final barrier; barrier count is uniform
// across waves (no divergence hazard).

using u16 = unsigned short;
typedef __bf16 bf16x8 __attribute__((ext_vector_type(8)));
typedef float f32x4 __attribute__((ext_vector_type(4)));

#define NCHUNK 16
#define CLEN   64
// chunk swizzle: quad j of row r lives at chunk r*4 + (j ^ ((r>>1)&3))
#define SWZ(row, q) ((q) ^ (((row) >> 1) & 3))

__device__ __forceinline__ float bf2f(u16 u) {
    union { unsigned int i; float f; } v; v.i = ((unsigned int)u) << 16; return v.f;
}
__device__ __forceinline__ u16 f2bf(float f) {
    union { float f; unsigned int i; } v; v.f = f;
    unsigned int x = v.i;
    return (u16)((x + 0x7FFFu + ((x >> 16) & 1u)) >> 16);   // RNE
}

// fp32 scratch carved out of the dead xp-column half of xz (rows x 8192 u16;
// cols 0..4095 dead after conv). h_loc: rows 0..1023, h_in: rows 1024..2047.
__device__ __forceinline__ float* hloc_ptr(u16* xzbase, int i) {
    return reinterpret_cast<float*>(xzbase + (size_t)(i >> 11) * 8192) + (i & 2047);
}
__device__ __forceinline__ float* hin_ptr(u16* xzbase, int i) {
    return reinterpret_cast<float*>(xzbase + (size_t)((i >> 11) + 1024) * 8192) + (i & 2047);
}

// ---------------- dtype detection -------------------------------------------
__global__ void detect_dtype(const u16* __restrict__ xraw, int* __restrict__ flag) {
    __shared__ int cnt[256];
    const int tid = threadIdx.x;
    int plausible = 0;
    for (int i = tid; i < 4096; i += 256) {
        const u16 v = xraw[2 * i];
        const int e = (v >> 7) & 0xFF;
        plausible += (e >= 100 && e <= 145) ? 1 : 0;
    }
    cnt[tid] = plausible;
    __syncthreads();
    for (int s = 128; s > 0; s >>= 1) {
        if (tid < s) cnt[tid] += cnt[tid + s];
        __syncthreads();
    }
    if (tid == 0) *flag = (cnt[0] > 2458) ? 1 : 0;
}

// ---------------- fused canonicalize (6 tensors) + x_dbl zero ---------------
__device__ __forceinline__ void cvt_seg(const void* src, u16* dst, int i,
                                        bool isbf) {
    dst[i] = isbf ? ((const u16*)src)[i] : f2bf(((const float*)src)[i]);
}
__global__ void cvt_fused(const void* __restrict__ x_raw, u16* __restrict__ xcan,
                          const void* __restrict__ cw_raw, u16* __restrict__ cw_c,
                          const void* __restrict__ cb_raw, u16* __restrict__ cb_c,
                          const void* __restrict__ bdt_raw, u16* __restrict__ bdt_c,
                          const void* __restrict__ Alog_raw, u16* __restrict__ Alog_c,
                          const void* __restrict__ D_raw, u16* __restrict__ D_c,
                          float* __restrict__ x_dbl,
                          const int* __restrict__ flag) {
    const bool isbf = (*flag != 0);
    int blk = blockIdx.x;
    const int tid = threadIdx.x;
    if (blk < 16384) { cvt_seg(x_raw, xcan, blk * 256 + tid, isbf); return; }
    blk -= 16384;
    if (blk < 48)  { cvt_seg(cw_raw, cw_c, blk * 256 + tid, isbf); return; }
    blk -= 48;
    if (blk < 16)  { cvt_seg(cb_raw, cb_c, blk * 256 + tid, isbf); return; }
    blk -= 16;
    if (blk < 16)  { cvt_seg(bdt_raw, bdt_c, blk * 256 + tid, isbf); return; }
    blk -= 16;
    if (blk < 256) { cvt_seg(Alog_raw, Alog_c, blk * 256 + tid, isbf); return; }
    blk -= 256;
    if (blk < 16)  { cvt_seg(D_raw, D_c, blk * 256 + tid, isbf); return; }
    blk -= 16;
    x_dbl[blk * 256 + tid] = 0.f;       // 1280 blocks: zero 2048*160 fp32
}

// ---------------- fused flag-aware transposes (4 tensors) -------------------
__device__ __forceinline__ void tr_tile(const void* in, u16* out, int R, int C,
                                        int bx, int by, int tx, int ty, bool isbf,
                                        u16 (*tile)[33]) {
    const int c0 = bx * 32, r0 = by * 32;
#pragma unroll
    for (int i = 0; i < 4; i++) {
        const size_t idx = (size_t)(r0 + ty + i * 8) * C + c0 + tx;
        tile[ty + i * 8][tx] = isbf ? ((const u16*)in)[idx]
                                    : f2bf(((const float*)in)[idx]);
    }
    __syncthreads();
#pragma unroll
    for (int i = 0; i < 4; i++)
        out[(size_t)(c0 + ty + i * 8) * R + r0 + tx] = tile[tx][ty + i * 8];
}
__global__ void transpose_fused(const void* __restrict__ Wi, u16* __restrict__ WiT,
                                const void* __restrict__ Wo, u16* __restrict__ WoT,
                                const void* __restrict__ Wd, u16* __restrict__ WdT,
                                const void* __restrict__ Wx, u16* __restrict__ WxT,
                                const int* __restrict__ flag) {
    __shared__ u16 tile[32][33];
    const bool isbf = (*flag != 0);
    const int tx = threadIdx.x, ty = threadIdx.y;   // (32,8)
    int blk = blockIdx.x;
    if (blk < 16384) { tr_tile(Wi, WiT, 2048, 8192, blk % 256, blk / 256, tx, ty, isbf, tile); return; }
    blk -= 16384;
    if (blk < 8192)  { tr_tile(Wo, WoT, 4096, 2048, blk % 64, blk / 64, tx, ty, isbf, tile); return; }
    blk -= 8192;
    if (blk < 512)   { tr_tile(Wd, WdT, 128, 4096, blk % 128, blk / 128, tx, ty, isbf, tile); return; }
    blk -= 512;
    tr_tile(Wx, WxT, 4096, 160, blk % 5, blk / 5, tx, ty, isbf, tile);   // 640 blocks
}

// ---------------- ring-4 deep-pipelined bf16 GEMM (2-phase K-step) ----------
// C[M,N] = A[M,K] * Bt[N,K]^T. 64*WM*WN threads; per-wave output
// (BM/WM) x (BN/WN). BK=32; LDS ring of 4 tile-buffers; staging runs 3 tiles
// ahead; per-tile s_waitcnt vmcnt(12) retires only the tile about to be
// consumed (4 loads/thread/stage in all instantiations). Raw s_barrier (no
// __syncthreads) so the compiler cannot force a vmcnt(0) drain.
// Compute is split into NPH=2 phases of 16 MFMA each, with per-phase
// s_barrier + setprio(1) around the MFMA cluster: waves drift within a
// phase so LDS-pipe and MFMA-pipe work overlap across waves (m201-style
// granularity: 2 phases per K=32 == 8 phases per K=128).
// Ring-4 WAR safety: tile t+3 overwrites buf[(t-1)&3], whose reads finished
// at iteration t-1's final phase barrier. Requires K>=96, K%32==0,
// M%BM==0, N%BN==0.
// MODE 0: bf16 store. MODE 1: flag-aware store (bf16/fp32), flag read AFTER
// the main loop so it cannot perturb the vmcnt ladder.
template <int BM, int BN, int THR>
__device__ __forceinline__ void stage_ring(const u16* __restrict__ Ab,
                                           const u16* __restrict__ Bb,
                                           int K, int k0, u16* dst, int tid)
{
    constexpr int CHA = BM * 4, CHB = BN * 4;
    static_assert(CHA % THR == 0 && CHB % THR == 0, "chunk/thread mismatch");
#pragma unroll
    for (int it = 0; it < CHA / THR; it++) {
        const int c = it * THR + tid;
        const int row = c >> 2, kc = SWZ(row, c & 3);
        __builtin_amdgcn_global_load_lds(
            (const __attribute__((address_space(1))) void*)(Ab + (size_t)row * K + k0 + kc * 8),
            (__attribute__((address_space(3))) void*)(dst + c * 8), 16, 0, 0);
    }
#pragma unroll
    for (int it = 0; it < CHB / THR; it++) {
        const int c = it * THR + tid;
        const int row = c >> 2, kc = SWZ(row, c & 3);
        __builtin_amdgcn_global_load_lds(
            (const __attribute__((address_space(1))) void*)(Bb + (size_t)row * K + k0 + kc * 8),
            (__attribute__((address_space(3))) void*)(dst + BM * 32 + c * 8), 16, 0, 0);
    }
}

template <int BM, int BN, int WM, int WN, int MODE>
__global__ __launch_bounds__(64 * WM * WN, 2) void gemm_ring(
    const u16* __restrict__ A, const u16* __restrict__ Bt, void* __restrict__ C,
    const int* __restrict__ oflagp, int M, int N, int K)
{
    constexpr int THR = 64 * WM * WN;
    constexpr int MT  = BM / (WM * 16);
    constexpr int NT  = BN / (WN * 16);
    constexpr int NPH = 2;                       // compute phases per K-tile
    constexpr int GM  = MT / NPH;                // mi-rows per phase
    constexpr int STG = (BM + BN) * 32;          // u16 per ring stage
    static_assert((BM * 4 + BN * 4) / THR == 4, "vmcnt ladder assumes 4 loads/thread/stage");
    static_assert(MT % NPH == 0, "MT must split into NPH phases");
    extern __shared__ u16 smem[];                // 4 * STG u16

    const int tid  = threadIdx.x;
    const int lane = tid & 63;
    const int wave = tid >> 6;
    const int wm = wave / WN, wn = wave % WN;
    const int q  = lane >> 4;                    // k-quad this lane consumes
    const int n0 = blockIdx.x * BN;
    const int m0 = blockIdx.y * BM;
    const int NTILE = K >> 5;                    // BK=32 tiles

    const u16* Ab = A  + (size_t)m0 * K;
    const u16* Bb = Bt + (size_t)n0 * K;

    // prologue: tiles 0..2 in flight (12 loads/thread)
    stage_ring<BM, BN, THR>(Ab, Bb, K, 0,  smem + 0 * STG, tid);
    stage_ring<BM, BN, THR>(Ab, Bb, K, 32, smem + 1 * STG, tid);
    stage_ring<BM, BN, THR>(Ab, Bb, K, 64, smem + 2 * STG, tid);

    f32x4 acc[MT][NT];
#pragma unroll
    for (int mi = 0; mi < MT; mi++)
#pragma unroll
        for (int ni = 0; ni < NT; ni++)
            acc[mi][ni] = (f32x4){0.f, 0.f, 0.f, 0.f};

    const int arow = wm * (MT * 16) + (lane & 15);
    const int brow = wn * (NT * 16) + (lane & 15);

    for (int t = 0; t < NTILE; t++) {
        const int tp = t + 3;
        if (tp < NTILE) {
            stage_ring<BM, BN, THR>(Ab, Bb, K, tp * 32, smem + (tp & 3) * STG, tid);
            asm volatile("s_waitcnt vmcnt(12)" ::: "memory");   // tile t landed
        } else if (tp == NTILE) {
            asm volatile("s_waitcnt vmcnt(8)" ::: "memory");
        } else if (tp == NTILE + 1) {
            asm volatile("s_waitcnt vmcnt(4)" ::: "memory");
        } else {
            asm volatile("s_waitcnt vmcnt(0)" ::: "memory");
        }
        __builtin_amdgcn_s_barrier();            // tile t visible to all

        const u16* As = smem + (t & 3) * STG;
        const u16* Bs = As + BM * 32;
        bf16x8 bfr[NT];
#pragma unroll
        for (int ni = 0; ni < NT; ni++) {
            const int r = brow + ni * 16;
            bfr[ni] = *reinterpret_cast<const bf16x8*>(&Bs[r * 32 + SWZ(r, q) * 8]);
        }
#pragma unroll
        for (int g = 0; g < NPH; g++) {
            bf16x8 af[GM];
#pragma unroll
            for (int i = 0; i < GM; i++) {
                const int r = arow + (g * GM + i) * 16;
                af[i] = *reinterpret_cast<const bf16x8*>(&As[r * 32 + SWZ(r, q) * 8]);
            }
            __builtin_amdgcn_s_setprio(1);
#pragma unroll
            for (int i = 0; i < GM; i++)
#pragma unroll
                for (int ni = 0; ni < NT; ni++)
                    acc[g * GM + i][ni] = __builtin_amdgcn_mfma_f32_16x16x32_bf16(
                        af[i], bfr[ni], acc[g * GM + i][ni], 0, 0, 0);
            __builtin_amdgcn_s_setprio(0);
            __builtin_amdgcn_sched_barrier(0);   // pin phase reads before barrier
            __builtin_amdgcn_s_barrier();        // phase boundary (last = exit)
        }
    }

    int oflag = 1;
    if constexpr (MODE == 1) oflag = *oflagp;    // after loop: vmcnt already 0

    const int rb = m0 + wm * (MT * 16) + (q << 2);
    const int cb = n0 + wn * (NT * 16) + (lane & 15);
#pragma unroll
    for (int mi = 0; mi < MT; mi++) {
#pragma unroll
        for (int ni = 0; ni < NT; ni++) {
            const int col = cb + ni * 16;
#pragma unroll
            for (int r = 0; r < 4; r++) {
                const int row = rb + mi * 16 + r;
                const float v = acc[mi][ni][r];
                if constexpr (MODE == 0) {
                    ((u16*)C)[(size_t)row * N + col] = f2bf(v);
                } else {
                    if (oflag) ((u16*)C)[(size_t)row * N + col] = f2bf(v);
                    else       ((float*)C)[(size_t)row * N + col] = v;
                }
            }
        }
    }
}

// ---------------- generic bf16 MFMA GEMM:  C[M,N] = A[M,K] * Bt[N,K]^T -------
// (kept for K3's split-K atomic path)
template <int BM, int BN, int BK, int WR, int WC, int MT, int NT, int MODE>
__global__ __launch_bounds__(256) void gemm_bt(
    const u16* __restrict__ A, const u16* __restrict__ Bt,
    void* __restrict__ C, const u16* __restrict__ bias,
    const int* __restrict__ oflagp,
    int M, int N, int K)
{
    static_assert(BK == 32, "BK=32 (one 16x16x32 MFMA k-slab)");
    __shared__ u16 As[BM * BK];
    __shared__ u16 Bs[BN * BK];

    const int tid  = threadIdx.x;
    const int lane = tid & 63;
    const int wave = tid >> 6;
    const int wm = wave / WC, wn = wave % WC;

    const int m0 = blockIdx.y * BM;
    const int n0 = blockIdx.x * BN;
    const int Kchunk = K / gridDim.z;
    const int kbeg = blockIdx.z * Kchunk;
    const int kend = kbeg + Kchunk;

    f32x4 acc[MT][NT];
#pragma unroll
    for (int mi = 0; mi < MT; mi++)
#pragma unroll
        for (int ni = 0; ni < NT; ni++)
            acc[mi][ni] = (f32x4){0.f, 0.f, 0.f, 0.f};

    const int q = lane >> 4;               // k-quad this lane consumes
    const int arow = wm * MT * 16 + (lane & 15);
    const int brow = wn * NT * 16 + (lane & 15);

    constexpr int CHA = BM * 4;            // 16B chunks in A tile
    constexpr int CHB = BN * 4;

    for (int k0 = kbeg; k0 < kend; k0 += BK) {
        __syncthreads();
        // async stage A tile: chunk c holds global quad (c&3)^((row>>1)&3)
#pragma unroll
        for (int it = 0; it < (CHA + 255) / 256; it++) {
            const int c = it * 256 + tid;
            if (CHA % 256 == 0 || c < CHA) {
                const int row = c >> 2, kc = SWZ(row, c & 3);
                const u16* gp = &A[(size_t)(m0 + row) * K + k0 + kc * 8];
                __builtin_amdgcn_global_load_lds(
                    (const __attribute__((address_space(1))) void*)gp,
                    (__attribute__((address_space(3))) void*)&As[c * 8], 16, 0, 0);
            }
        }
#pragma unroll
        for (int it = 0; it < (CHB + 255) / 256; it++) {
            const int c = it * 256 + tid;
            if (CHB % 256 == 0 || c < CHB) {
                const int row = c >> 2, kc = SWZ(row, c & 3);
                const u16* gp = &Bt[(size_t)(n0 + row) * K + k0 + kc * 8];
                __builtin_amdgcn_global_load_lds(
                    (const __attribute__((address_space(1))) void*)gp,
                    (__attribute__((address_space(3))) void*)&Bs[c * 8], 16, 0, 0);
            }
        }
        __syncthreads();

        bf16x8 af[MT], bfr[NT];
#pragma unroll
        for (int mi = 0; mi < MT; mi++) {
            const int row = arow + mi * 16;
            af[mi] = *reinterpret_cast<const bf16x8*>(&As[row * BK + SWZ(row, q) * 8]);
        }
#pragma unroll
        for (int ni = 0; ni < NT; ni++) {
            const int row = brow + ni * 16;
            bfr[ni] = *reinterpret_cast<const bf16x8*>(&Bs[row * BK + SWZ(row, q) * 8]);
        }
#pragma unroll
        for (int mi = 0; mi < MT; mi++)
#pragma unroll
            for (int ni = 0; ni < NT; ni++)
                acc[mi][ni] = __builtin_amdgcn_mfma_f32_16x16x32_bf16(
                    af[mi], bfr[ni], acc[mi][ni], 0, 0, 0);
    }

    const int rb = m0 + wm * MT * 16 + ((lane >> 4) << 2);
    const int cb = n0 + wn * NT * 16 + (lane & 15);
#pragma unroll
    for (int mi = 0; mi < MT; mi++) {
#pragma unroll
        for (int ni = 0; ni < NT; ni++) {
            const int col = cb + ni * 16;
#pragma unroll
            for (int r = 0; r < 4; r++) {
                const int row = rb + mi * 16 + r;
                const float v = acc[mi][ni][r];
                if constexpr (MODE == 0) {
                    ((u16*)C)[(size_t)row * N + col] = f2bf(v);
                } else if constexpr (MODE == 4) {
                    atomicAdd(((float*)C) + (size_t)row * N + col, v);
                }
            }
        }
    }
}

// ---------------- dedicated dt GEMM: dt = softplus(dtin @ W_dtT^T + b) ------
// M=2048, N=4096, K=128 (whole K staged once). 64x64 tile, 2048 blocks.
// Epilogue: acc -> LDS fp32 [64][68] -> float4 coalesced global stores.
__global__ __launch_bounds__(256) void dt_gemm(
    const u16* __restrict__ A,      // dtin  [2048 x 128] bf16
    const u16* __restrict__ Bt,     // W_dtT [4096 x 128] bf16
    float* __restrict__ C,          // dtv   [2048 x 4096] fp32
    const u16* __restrict__ bias)   // b_dt  [4096] bf16
{
    __shared__ ulong4 smem_raw[2048];            // 32 KB
    u16* As = (u16*)smem_raw;                    // [64][128] swizzled bf16
    u16* Bs = As + 64 * 128;                     // [64][128] swizzled bf16
    float* Cs = (float*)smem_raw;                // [64][68] fp32 (aliases As/Bs)

    const int tid  = threadIdx.x;
    const int lane = tid & 63;
    const int wave = tid >> 6;
    const int n0 = blockIdx.x * 64;
    const int m0 = blockIdx.y * 64;

    // stage A and B tiles: 64 rows x 16 chunks (16 B) each, 4 iters x 256 thr.
#pragma unroll
    for (int it = 0; it < 4; it++) {
        const int c = it * 256 + tid;
        const int row = c >> 4, cc = (c & 15) ^ (row & 7);
        const u16* gp = &A[(size_t)(m0 + row) * 128 + cc * 8];
        __builtin_amdgcn_global_load_lds(
            (const __attribute__((address_space(1))) void*)gp,
            (__attribute__((address_space(3))) void*)&As[c * 8], 16, 0, 0);
    }
#pragma unroll
    for (int it = 0; it < 4; it++) {
        const int c = it * 256 + tid;
        const int row = c >> 4, cc = (c & 15) ^ (row & 7);
        const u16* gp = &Bt[(size_t)(n0 + row) * 128 + cc * 8];
        __builtin_amdgcn_global_load_lds(
            (const __attribute__((address_space(1))) void*)gp,
            (__attribute__((address_space(3))) void*)&Bs[c * 8], 16, 0, 0);
    }
    __syncthreads();

    // wave w owns rows m0 + w*16 .. +15, all 64 cols of the tile.
    const int q  = lane >> 4;                 // k-quad this lane consumes
    const int ar = wave * 16 + (lane & 15);   // A row within tile
    f32x4 acc[4];
#pragma unroll
    for (int ni = 0; ni < 4; ni++) acc[ni] = (f32x4){0.f, 0.f, 0.f, 0.f};

#pragma unroll
    for (int kk = 0; kk < 4; kk++) {          // 4 k-slabs of 32
        const int cA = kk * 4 + q;            // 16B chunk index within row
        const bf16x8 af = *reinterpret_cast<const bf16x8*>(
            &As[(ar * 16 + (cA ^ (ar & 7))) * 8]);
#pragma unroll
        for (int ni = 0; ni < 4; ni++) {
            const int br = ni * 16 + (lane & 15);
            const bf16x8 bfr = *reinterpret_cast<const bf16x8*>(
                &Bs[(br * 16 + (cA ^ (br & 7))) * 8]);
            acc[ni] = __builtin_amdgcn_mfma_f32_16x16x32_bf16(af, bfr, acc[ni], 0, 0, 0);
        }
    }
    __syncthreads();   // all As/Bs reads done before Cs overwrites them

    // fragment -> LDS fp32 tile (stride 68 breaks the 256B bank aliasing)
#pragma unroll
    for (int ni = 0; ni < 4; ni++) {
        const int col = ni * 16 + (lane & 15);
#pragma unroll
        for (int r = 0; r < 4; r++) {
            const int rowl = wave * 16 + q * 4 + r;
            Cs[rowl * 68 + col] = acc[ni][r];
        }
    }
    __syncthreads();

    // LDS -> global: 4 passes x float4 per thread; bias + softplus fused.
#pragma unroll
    for (int p = 0; p < 4; p++) {
        const int rowl = p * 16 + (tid >> 4);
        const int c0 = (tid & 15) * 4;
        float4 v = *reinterpret_cast<const float4*>(&Cs[rowl * 68 + c0]);
        float* vp = reinterpret_cast<float*>(&v);
#pragma unroll
        for (int j = 0; j < 4; j++) {
            const float x = vp[j] + bf2f(bias[n0 + c0 + j]);
            // softplus(x) = max(x,0) + log1p(exp(-|x|)); fast hw exp/log
            vp[j] = fmaxf(x, 0.f) + __logf(1.f + __expf(-fabsf(x)));
        }
        *reinterpret_cast<float4*>(&C[(size_t)(m0 + rowl) * 4096 + n0 + c0]) = v;
    }
}

// ---------------- depthwise conv3 + bias + silu -----------------------------
__global__ void conv_silu(const u16* __restrict__ xz, const u16* __restrict__ conv_w,
                          const u16* __restrict__ conv_b, u16* __restrict__ xc) {
    const int idx = blockIdx.x * 256 + threadIdx.x;    // 2048*4096
    const int row = idx >> 12, c = idx & 4095;
    const int l = row & 1023;
    const float w0 = bf2f(conv_w[c * 3 + 0]);
    const float w1 = bf2f(conv_w[c * 3 + 1]);
    const float w2 = bf2f(conv_w[c * 3 + 2]);
    const float x0 = bf2f(xz[(size_t)row * 8192 + c]);
    const float xm = (l > 0)    ? bf2f(xz[(size_t)(row - 1) * 8192 + c]) : 0.f;
    const float xp = (l < 1023) ? bf2f(xz[(size_t)(row + 1) * 8192 + c]) : 0.f;
    float v = w0 * xm + w1 * x0 + w2 * xp + bf2f(conv_b[c]);
    v = v / (1.f + __expf(-v));
    xc[(size_t)row * 4096 + c] = f2bf(v);
}

// ---------------- x_dbl[:, :128] -> bf16 ------------------------------------
__global__ void cvt_dtin(const float* __restrict__ x_dbl, u16* __restrict__ dtin) {
    const int idx = blockIdx.x * 256 + threadIdx.x;    // 2048*128
    const int row = idx >> 7, c = idx & 127;
    dtin[idx] = f2bf(x_dbl[(size_t)row * 160 + c]);
}

// ---------------- S1: per-chunk local scan (h_in = 0), lane = channel -------
// grid (NCHUNK, 16, 2), 256 threads: lane owns all 16 states of one channel.
__global__ __launch_bounds__(256) void scan_p1(
    const float* __restrict__ dt, const u16* __restrict__ xc,
    const float* __restrict__ x_dbl, const u16* __restrict__ A_log,
    float* __restrict__ Parr, u16* __restrict__ xzbase)
{
    __shared__ float Bsm[CLEN][16];
    const int tid = threadIdx.x;
    const int nc = blockIdx.x, cg = blockIdx.y, b = blockIdx.z;
    const int ch = cg * 256 + tid;
    const size_t row0 = (size_t)b * 1024 + nc * CLEN;

    {   // stage B[t][s]: 64 rows x 16 floats; 256 threads x 1 float4
        const int t = tid >> 2, q = tid & 3;
        const float4 v = *(const float4*)&x_dbl[(row0 + t) * 160 + 128 + q * 4];
        *(float4*)&Bsm[t][q * 4] = v;
    }
    __syncthreads();

    float A_s[16], h[16];
#pragma unroll
    for (int s = 0; s < 16; s++) {
        A_s[s] = -__expf(bf2f(A_log[ch * 16 + s]));
        h[s] = 0.f;
    }
    float Sdt = 0.f;

    float dt_v = dt[row0 * 4096 + ch];
    float u_v  = bf2f(xc[row0 * 4096 + ch]);
    for (int t = 0; t < CLEN; t++) {
        const int tn = (t + 1 < CLEN) ? t + 1 : t;
        const float dt_n = dt[(row0 + tn) * 4096 + ch];
        const float u_n  = bf2f(xc[(row0 + tn) * 4096 + ch]);
        const float dtu = dt_v * u_v;
        Sdt += dt_v;
        const f32x4* Brow = (const f32x4*)&Bsm[t][0];
        const f32x4 B0 = Brow[0], B1 = Brow[1], B2 = Brow[2], B3 = Brow[3];
#pragma unroll
        for (int s = 0; s < 16; s++) {
            const float Bs_ = (s < 4 ? B0[s & 3] : s < 8 ? B1[s & 3] : s < 12 ? B2[s & 3] : B3[s & 3]);
            const float dA = __expf(dt_v * A_s[s]);
            h[s] = dA * h[s] + dtu * Bs_;
        }
        dt_v = dt_n; u_v = u_n;
    }
    const int i0 = (((b * NCHUNK + nc) * 4096) + ch) * 16;
#pragma unroll
    for (int s = 0; s < 16; s++) {
        Parr[i0 + s] = __expf(A_s[s] * Sdt);   // prod(exp(dt*A)) = exp(A*sum dt)
        *hloc_ptr(xzbase, i0 + s) = h[s];
    }
}

// ---------------- S2: combine chunk summaries -> h_in -----------------------
__global__ __launch_bounds__(256) void scan_p2(
    const float* __restrict__ Parr, u16* __restrict__ xzbase)
{
    const int tid = threadIdx.x;
    const int lane = tid & 63, wave = tid >> 6;
    const int blk = blockIdx.x;
    const int b = blk >> 8, cg = blk & 255;
    const int c_local = lane & 3, s = lane >> 2;
    const int ch = cg * 16 + wave * 4 + c_local;

    float Pv[NCHUNK], hl[NCHUNK];
#pragma unroll
    for (int c = 0; c < NCHUNK; c++) {
        const int i = (((b * NCHUNK + c) * 4096) + ch) * 16 + s;
        Pv[c] = Parr[i];
        hl[c] = *hloc_ptr(xzbase, i);
    }
    float hin = 0.f;
#pragma unroll
    for (int c = 0; c < NCHUNK; c++) {
        const int i = (((b * NCHUNK + c) * 4096) + ch) * 16 + s;
        *hin_ptr(xzbase, i) = hin;
        hin = Pv[c] * hin + hl[c];
    }
}

// ---------------- S3: rescan with h_in; fused gate; lane = channel ----------
__global__ __launch_bounds__(256) void scan_p3(
    const float* __restrict__ dt, const u16* __restrict__ xc,
    const float* __restrict__ x_dbl, const u16* __restrict__ xz,
    const u16* __restrict__ A_log, const u16* __restrict__ Dp,
    u16* __restrict__ yg, u16* __restrict__ xzbase)
{
    __shared__ float BCs[CLEN][32];   // [t][0..15]=B, [t][16..31]=C
    const int tid = threadIdx.x;
    const int nc = blockIdx.x, cg = blockIdx.y, b = blockIdx.z;
    const int ch = cg * 256 + tid;
    const size_t row0 = (size_t)b * 1024 + nc * CLEN;

#pragma unroll
    for (int it = 0; it < 2; it++) {   // 64 rows x 32 floats; 512 float4
        const int c = it * 256 + tid;
        const int t = c >> 3, q = c & 7;
        const float4 v = *(const float4*)&x_dbl[(row0 + t) * 160 + 128 + q * 4];
        *(float4*)&BCs[t][q * 4] = v;
    }
    __syncthreads();

    float A_s[16], h[16];
    const int i0 = (((b * NCHUNK + nc) * 4096) + ch) * 16;
#pragma unroll
    for (int s = 0; s < 16; s++) {
        A_s[s] = -__expf(bf2f(A_log[ch * 16 + s]));
        h[s] = *hin_ptr(xzbase, i0 + s);
    }
    const float D_ch = bf2f(Dp[ch]);

    float dt_v = dt[row0 * 4096 + ch];
    float u_v  = bf2f(xc[row0 * 4096 + ch]);
    float z_v  = bf2f(xz[row0 * 8192 + 4096 + ch]);
    for (int t = 0; t < CLEN; t++) {
        const int tn = (t + 1 < CLEN) ? t + 1 : t;
        const size_t rn = row0 + tn;
        const float dt_n = dt[rn * 4096 + ch];
        const float u_n  = bf2f(xc[rn * 4096 + ch]);
        const float z_n  = bf2f(xz[rn * 8192 + 4096 + ch]);
        const float dtu = dt_v * u_v;

        const f32x4* Row = (const f32x4*)&BCs[t][0];
        const f32x4 B0 = Row[0], B1 = Row[1], B2 = Row[2], B3 = Row[3];
        const f32x4 C0 = Row[4], C1 = Row[5], C2 = Row[6], C3 = Row[7];

        float y0 = 0.f, y1 = 0.f, y2 = 0.f, y3 = 0.f;
#pragma unroll
        for (int s = 0; s < 16; s++) {
            const float Bs_ = (s < 4 ? B0[s & 3] : s < 8 ? B1[s & 3] : s < 12 ? B2[s & 3] : B3[s & 3]);
            const float Cs_ = (s < 4 ? C0[s & 3] : s < 8 ? C1[s & 3] : s < 12 ? C2[s & 3] : C3[s & 3]);
            const float dA = __expf(dt_v * A_s[s]);
            h[s] = dA * h[s] + dtu * Bs_;
            const float hc = h[s] * Cs_;
            if ((s & 3) == 0) y0 += hc; else if ((s & 3) == 1) y1 += hc;
            else if ((s & 3) == 2) y2 += hc; else y3 += hc;
        }
        const float y = (y0 + y1) + (y2 + y3);
        const float silu_z = z_v / (1.f + __expf(-z_v));
        yg[(row0 + t) * 4096 + ch] = f2bf((y + u_v * D_ch) * silu_z);
        dt_v = dt_n; u_v = u_n; z_v = z_n;
    }
}

extern "C" void kernel_launch(void* const* d_in, const int* in_sizes, int n_in,
                              void* d_out, int out_size, void* d_ws, size_t ws_size,
                              hipStream_t stream)
{
    const void* x_raw      = d_in[0];   // (2,1024,2048)
    const void* W_in_raw   = d_in[1];   // (2048,8192)
    const void* conv_w_raw = d_in[2];   // (4096,1,3)
    const void* conv_b_raw = d_in[3];   // (4096)
    const void* W_x_raw    = d_in[4];   // (4096,160)
    const void* W_dt_raw   = d_in[5];   // (128,4096)
    const void* b_dt_raw   = d_in[6];   // (4096)
    const void* A_log_raw  = d_in[7];   // (4096,16)
    const void* D_raw      = d_in[8];   // (4096)
    const void* W_out_raw  = d_in[9];   // (4096,2048)

    char* ws = (char*)d_ws;
    size_t off = 0;
    auto alloc = [&](size_t bytes) { char* p = ws + off; off += (bytes + 255) & ~(size_t)255; return p; };
    int*   flag   = (int*)  alloc(4);
    u16*   W_inT  = (u16*)  alloc(8192ULL * 2048 * 2);   // 32 MB (aliased by dt fp32 after K1)
    u16*   W_outT = (u16*)  alloc(2048ULL * 4096 * 2);   // 16 MB
    u16*   W_dtT  = (u16*)  alloc(4096ULL * 128 * 2);    // 1 MB
    u16*   W_xT   = (u16*)  alloc(160ULL * 4096 * 2);    // 1.25 MB
    u16*   xz     = (u16*)  alloc(2048ULL * 8192 * 2);   // 32 MB (xp half reused as h_loc/h_in)
    u16*   xc     = (u16*)  alloc(2048ULL * 4096 * 2);   // 16 MB
    float* x_dbl  = (float*)alloc(2048ULL * 160 * 4);    // 1.25 MB
    u16*   dtin   = (u16*)  alloc(2048ULL * 128 * 2);    // 0.5 MB
    u16*   yg     = (u16*)  alloc(2048ULL * 4096 * 2);   // 16 MB
    u16*   xcan   = (u16*)  alloc(2048ULL * 2048 * 2);   // 8 MB (reused as Parr fp32)
    u16*   cw_c   = (u16*)  alloc(12288 * 2);
    u16*   cb_c   = (u16*)  alloc(4096 * 2);
    u16*   bdt_c  = (u16*)  alloc(4096 * 2);
    u16*   Alog_c = (u16*)  alloc(65536 * 2);
    u16*   D_c    = (u16*)  alloc(4096 * 2);
    float* dtv    = (float*)W_inT;   // alias: W_inT dead after K1 (32 MB exact)
    float* Parr   = (float*)xcan;    // alias: xcan dead after K1 (8 MB exact)

    // D) dtype flag, fused canonicalize + x_dbl zero
    detect_dtype<<<1, 256, 0, stream>>>((const u16*)x_raw, flag);
    cvt_fused<<<16384 + 48 + 16 + 16 + 256 + 16 + 1280, 256, 0, stream>>>(
        x_raw, xcan, conv_w_raw, cw_c, conv_b_raw, cb_c, b_dt_raw, bdt_c,
        A_log_raw, Alog_c, D_raw, D_c, x_dbl, flag);

    // T) fused transposes
    transpose_fused<<<16384 + 8192 + 512 + 640, dim3(32, 8), 0, stream>>>(
        W_in_raw, W_inT, W_out_raw, W_outT, W_dt_raw, W_dtT, W_x_raw, W_xT, flag);

    // K1: xz = x @ W_in   (M=2048, N=8192, K=2048), 256^2 ring-4 2-phase
    (void)hipFuncSetAttribute(
        reinterpret_cast<const void*>(&gemm_ring<256, 256, 2, 4, 0>),
        hipFuncAttributeMaxDynamicSharedMemorySize, 131072);
    gemm_ring<256, 256, 2, 4, 0><<<dim3(8192 / 256, 2048 / 256), 512, 131072, stream>>>(
        xcan, W_inT, xz, nullptr, 2048, 8192, 2048);

    // K2: conv + bias + silu
    conv_silu<<<(2048 * 4096) / 256, 256, 0, stream>>>(xz, cw_c, cb_c, xc);

    // K3: x_dbl = xc @ W_x   (split-K=8, atomic fp32; x_dbl zeroed in cvt_fused)
    gemm_bt<64, 160, 32, 4, 1, 1, 10, 4>
        <<<dim3(1, 2048 / 64, 8), 256, 0, stream>>>(xc, W_xT, x_dbl, nullptr, nullptr, 2048, 160, 4096);

    cvt_dtin<<<(2048 * 128) / 256, 256, 0, stream>>>(x_dbl, dtin);

    // K4: dt = softplus(dtin @ W_dt + b_dt)   (fp32 out, dedicated kernel)
    dt_gemm<<<dim3(4096 / 64, 2048 / 64), 256, 0, stream>>>(dtin, W_dtT, dtv, bdt_c);

    // S1/S2/S3: chunked selective scan (lane=channel) with fused gating
    scan_p1<<<dim3(NCHUNK, 16, 2), 256, 0, stream>>>(dtv, xc, x_dbl, Alog_c, Parr, xz);
    scan_p2<<<512, 256, 0, stream>>>(Parr, xz);
    scan_p3<<<dim3(NCHUNK, 16, 2), 256, 0, stream>>>(dtv, xc, x_dbl, xz, Alog_c, D_c, yg, xz);

    // K6: out = yg @ W_out   (M=2048, N=2048, K=4096), 128^2 ring-4 2-phase
    (void)hipFuncSetAttribute(
        reinterpret_cast<const void*>(&gemm_ring<128, 128, 2, 2, 1>),
        hipFuncAttributeMaxDynamicSharedMemorySize, 65536);
    gemm_ring<128, 128, 2, 2, 1><<<dim3(2048 / 128, 2048 / 128), 256, 65536, stream>>>(
        yg, W_outT, d_out, flag, 2048, 2048, 4096);
}

// Round 6
// 430.215 us; speedup vs baseline: 1.0433x; 1.0433x over previous
//
#include <hip/hip_runtime.h>
#include <hip/hip_bf16.h>

// Selective SSM (Mamba-style): B=2, L=1024, H=2048, E=2 -> d=4096, S=16, R=128.
// Round 13: tail fixes (GEMMs untouched). (a) scan_p1/p3: h_loc/h_in/Parr
// accesses were 16 scalar fp32 ops/thread at 64B thread-stride (64-line
// scatter per wave-op) -> float4 x4. (b) conv_silu vectorized to 8 ch/thread
// (u16x8 loads/stores; was scalar bf16). (c) transpose_fused: 64x32 input
// tiles, u32 transposed writes (was 2B/lane scalar stores).

using u16 = unsigned short;
typedef __bf16 bf16x8 __attribute__((ext_vector_type(8)));
typedef float f32x4 __attribute__((ext_vector_type(4)));
typedef u16 u16x8 __attribute__((ext_vector_type(8)));

#define NCHUNK 16
#define CLEN   64
// chunk swizzle: quad j of row r lives at chunk r*4 + (j ^ ((r>>1)&3))
#define SWZ(row, q) ((q) ^ (((row) >> 1) & 3))

__device__ __forceinline__ float bf2f(u16 u) {
    union { unsigned int i; float f; } v; v.i = ((unsigned int)u) << 16; return v.f;
}
__device__ __forceinline__ u16 f2bf(float f) {
    union { float f; unsigned int i; } v; v.f = f;
    unsigned int x = v.i;
    return (u16)((x + 0x7FFFu + ((x >> 16) & 1u)) >> 16);   // RNE
}

// fp32 scratch carved out of the dead xp-column half of xz (rows x 8192 u16;
// cols 0..4095 dead after conv). h_loc: rows 0..1023, h_in: rows 1024..2047.
__device__ __forceinline__ float* hloc_ptr(u16* xzbase, int i) {
    return reinterpret_cast<float*>(xzbase + (size_t)(i >> 11) * 8192) + (i & 2047);
}
__device__ __forceinline__ float* hin_ptr(u16* xzbase, int i) {
    return reinterpret_cast<float*>(xzbase + (size_t)((i >> 11) + 1024) * 8192) + (i & 2047);
}

// ---------------- dtype detection -------------------------------------------
__global__ void detect_dtype(const u16* __restrict__ xraw, int* __restrict__ flag) {
    __shared__ int cnt[256];
    const int tid = threadIdx.x;
    int plausible = 0;
    for (int i = tid; i < 4096; i += 256) {
        const u16 v = xraw[2 * i];
        const int e = (v >> 7) & 0xFF;
        plausible += (e >= 100 && e <= 145) ? 1 : 0;
    }
    cnt[tid] = plausible;
    __syncthreads();
    for (int s = 128; s > 0; s >>= 1) {
        if (tid < s) cnt[tid] += cnt[tid + s];
        __syncthreads();
    }
    if (tid == 0) *flag = (cnt[0] > 2458) ? 1 : 0;
}

// ---------------- fused canonicalize (6 tensors) + x_dbl zero ---------------
__device__ __forceinline__ void cvt_seg(const void* src, u16* dst, int i,
                                        bool isbf) {
    dst[i] = isbf ? ((const u16*)src)[i] : f2bf(((const float*)src)[i]);
}
__global__ void cvt_fused(const void* __restrict__ x_raw, u16* __restrict__ xcan,
                          const void* __restrict__ cw_raw, u16* __restrict__ cw_c,
                          const void* __restrict__ cb_raw, u16* __restrict__ cb_c,
                          const void* __restrict__ bdt_raw, u16* __restrict__ bdt_c,
                          const void* __restrict__ Alog_raw, u16* __restrict__ Alog_c,
                          const void* __restrict__ D_raw, u16* __restrict__ D_c,
                          float* __restrict__ x_dbl,
                          const int* __restrict__ flag) {
    const bool isbf = (*flag != 0);
    int blk = blockIdx.x;
    const int tid = threadIdx.x;
    if (blk < 16384) { cvt_seg(x_raw, xcan, blk * 256 + tid, isbf); return; }
    blk -= 16384;
    if (blk < 48)  { cvt_seg(cw_raw, cw_c, blk * 256 + tid, isbf); return; }
    blk -= 48;
    if (blk < 16)  { cvt_seg(cb_raw, cb_c, blk * 256 + tid, isbf); return; }
    blk -= 16;
    if (blk < 16)  { cvt_seg(bdt_raw, bdt_c, blk * 256 + tid, isbf); return; }
    blk -= 16;
    if (blk < 256) { cvt_seg(Alog_raw, Alog_c, blk * 256 + tid, isbf); return; }
    blk -= 256;
    if (blk < 16)  { cvt_seg(D_raw, D_c, blk * 256 + tid, isbf); return; }
    blk -= 16;
    x_dbl[blk * 256 + tid] = 0.f;       // 1280 blocks: zero 2048*160 fp32
}

// ---------------- fused flag-aware transposes (4 tensors) -------------------
// 64(rows) x 32(cols) input tile; transposed writes as u32 (2 elems/lane).
__device__ __forceinline__ void tr_tile(const void* in, u16* out, int R, int C,
                                        int bx, int by, int tx, int ty, bool isbf,
                                        u16 (*tile)[33]) {
    const int c0 = bx * 32, r0 = by * 64;
#pragma unroll
    for (int i = 0; i < 8; i++) {
        const int rl = ty + i * 8;
        const size_t idx = (size_t)(r0 + rl) * C + c0 + tx;
        tile[rl][tx] = isbf ? ((const u16*)in)[idx]
                            : f2bf(((const float*)in)[idx]);
    }
    __syncthreads();
#pragma unroll
    for (int i = 0; i < 4; i++) {
        const int w = ty + i * 8;                       // output row-local 0..31
        union { u16 h[2]; unsigned int u; } p;
        p.h[0] = tile[2 * tx][w];
        p.h[1] = tile[2 * tx + 1][w];
        *reinterpret_cast<unsigned int*>(&out[(size_t)(c0 + w) * R + r0 + 2 * tx]) = p.u;
    }
}
__global__ void transpose_fused(const void* __restrict__ Wi, u16* __restrict__ WiT,
                                const void* __restrict__ Wo, u16* __restrict__ WoT,
                                const void* __restrict__ Wd, u16* __restrict__ WdT,
                                const void* __restrict__ Wx, u16* __restrict__ WxT,
                                const int* __restrict__ flag) {
    __shared__ u16 tile[64][33];
    const bool isbf = (*flag != 0);
    const int tx = threadIdx.x, ty = threadIdx.y;   // (32,8)
    int blk = blockIdx.x;
    if (blk < 8192) { tr_tile(Wi, WiT, 2048, 8192, blk % 256, blk / 256, tx, ty, isbf, tile); return; }
    blk -= 8192;
    if (blk < 4096) { tr_tile(Wo, WoT, 4096, 2048, blk % 64, blk / 64, tx, ty, isbf, tile); return; }
    blk -= 4096;
    if (blk < 256)  { tr_tile(Wd, WdT, 128, 4096, blk % 128, blk / 128, tx, ty, isbf, tile); return; }
    blk -= 256;
    tr_tile(Wx, WxT, 4096, 160, blk % 5, blk / 5, tx, ty, isbf, tile);   // 320 blocks
}

// ---------------- ring-4 deep-pipelined bf16 GEMM (2-phase K-step) ----------
// C[M,N] = A[M,K] * Bt[N,K]^T. 64*WM*WN threads; per-wave output
// (BM/WM) x (BN/WN). BK=32; LDS ring of 4 tile-buffers; staging runs 3 tiles
// ahead; per-tile s_waitcnt vmcnt(12) retires only the tile about to be
// consumed (4 loads/thread/stage in all instantiations). Raw s_barrier (no
// __syncthreads) so the compiler cannot force a vmcnt(0) drain.
// Compute split into NPH=2 phases of 16 MFMA with setprio around the cluster.
// Ring-4 WAR safety: tile t+3 overwrites buf[(t-1)&3], whose reads finished
// at iteration t-1's final phase barrier. Requires K>=96, K%32==0,
// M%BM==0, N%BN==0.
template <int BM, int BN, int THR>
__device__ __forceinline__ void stage_ring(const u16* __restrict__ Ab,
                                           const u16* __restrict__ Bb,
                                           int K, int k0, u16* dst, int tid)
{
    constexpr int CHA = BM * 4, CHB = BN * 4;
    static_assert(CHA % THR == 0 && CHB % THR == 0, "chunk/thread mismatch");
#pragma unroll
    for (int it = 0; it < CHA / THR; it++) {
        const int c = it * THR + tid;
        const int row = c >> 2, kc = SWZ(row, c & 3);
        __builtin_amdgcn_global_load_lds(
            (const __attribute__((address_space(1))) void*)(Ab + (size_t)row * K + k0 + kc * 8),
            (__attribute__((address_space(3))) void*)(dst + c * 8), 16, 0, 0);
    }
#pragma unroll
    for (int it = 0; it < CHB / THR; it++) {
        const int c = it * THR + tid;
        const int row = c >> 2, kc = SWZ(row, c & 3);
        __builtin_amdgcn_global_load_lds(
            (const __attribute__((address_space(1))) void*)(Bb + (size_t)row * K + k0 + kc * 8),
            (__attribute__((address_space(3))) void*)(dst + BM * 32 + c * 8), 16, 0, 0);
    }
}

template <int BM, int BN, int WM, int WN, int MODE>
__global__ __launch_bounds__(64 * WM * WN, 2) void gemm_ring(
    const u16* __restrict__ A, const u16* __restrict__ Bt, void* __restrict__ C,
    const int* __restrict__ oflagp, int M, int N, int K)
{
    constexpr int THR = 64 * WM * WN;
    constexpr int MT  = BM / (WM * 16);
    constexpr int NT  = BN / (WN * 16);
    constexpr int NPH = 2;                       // compute phases per K-tile
    constexpr int GM  = MT / NPH;                // mi-rows per phase
    constexpr int STG = (BM + BN) * 32;          // u16 per ring stage
    static_assert((BM * 4 + BN * 4) / THR == 4, "vmcnt ladder assumes 4 loads/thread/stage");
    static_assert(MT % NPH == 0, "MT must split into NPH phases");
    extern __shared__ u16 smem[];                // 4 * STG u16

    const int tid  = threadIdx.x;
    const int lane = tid & 63;
    const int wave = tid >> 6;
    const int wm = wave / WN, wn = wave % WN;
    const int q  = lane >> 4;                    // k-quad this lane consumes
    const int n0 = blockIdx.x * BN;
    const int m0 = blockIdx.y * BM;
    const int NTILE = K >> 5;                    // BK=32 tiles

    const u16* Ab = A  + (size_t)m0 * K;
    const u16* Bb = Bt + (size_t)n0 * K;

    // prologue: tiles 0..2 in flight (12 loads/thread)
    stage_ring<BM, BN, THR>(Ab, Bb, K, 0,  smem + 0 * STG, tid);
    stage_ring<BM, BN, THR>(Ab, Bb, K, 32, smem + 1 * STG, tid);
    stage_ring<BM, BN, THR>(Ab, Bb, K, 64, smem + 2 * STG, tid);

    f32x4 acc[MT][NT];
#pragma unroll
    for (int mi = 0; mi < MT; mi++)
#pragma unroll
        for (int ni = 0; ni < NT; ni++)
            acc[mi][ni] = (f32x4){0.f, 0.f, 0.f, 0.f};

    const int arow = wm * (MT * 16) + (lane & 15);
    const int brow = wn * (NT * 16) + (lane & 15);

    for (int t = 0; t < NTILE; t++) {
        const int tp = t + 3;
        if (tp < NTILE) {
            stage_ring<BM, BN, THR>(Ab, Bb, K, tp * 32, smem + (tp & 3) * STG, tid);
            asm volatile("s_waitcnt vmcnt(12)" ::: "memory");   // tile t landed
        } else if (tp == NTILE) {
            asm volatile("s_waitcnt vmcnt(8)" ::: "memory");
        } else if (tp == NTILE + 1) {
            asm volatile("s_waitcnt vmcnt(4)" ::: "memory");
        } else {
            asm volatile("s_waitcnt vmcnt(0)" ::: "memory");
        }
        __builtin_amdgcn_s_barrier();            // tile t visible to all

        const u16* As = smem + (t & 3) * STG;
        const u16* Bs = As + BM * 32;
        bf16x8 bfr[NT];
#pragma unroll
        for (int ni = 0; ni < NT; ni++) {
            const int r = brow + ni * 16;
            bfr[ni] = *reinterpret_cast<const bf16x8*>(&Bs[r * 32 + SWZ(r, q) * 8]);
        }
#pragma unroll
        for (int g = 0; g < NPH; g++) {
            bf16x8 af[GM];
#pragma unroll
            for (int i = 0; i < GM; i++) {
                const int r = arow + (g * GM + i) * 16;
                af[i] = *reinterpret_cast<const bf16x8*>(&As[r * 32 + SWZ(r, q) * 8]);
            }
            __builtin_amdgcn_s_setprio(1);
#pragma unroll
            for (int i = 0; i < GM; i++)
#pragma unroll
                for (int ni = 0; ni < NT; ni++)
                    acc[g * GM + i][ni] = __builtin_amdgcn_mfma_f32_16x16x32_bf16(
                        af[i], bfr[ni], acc[g * GM + i][ni], 0, 0, 0);
            __builtin_amdgcn_s_setprio(0);
            __builtin_amdgcn_sched_barrier(0);   // pin phase reads before barrier
            __builtin_amdgcn_s_barrier();        // phase boundary (last = exit)
        }
    }

    int oflag = 1;
    if constexpr (MODE == 1) oflag = *oflagp;    // after loop: vmcnt already 0

    const int rb = m0 + wm * (MT * 16) + (q << 2);
    const int cb = n0 + wn * (NT * 16) + (lane & 15);
#pragma unroll
    for (int mi = 0; mi < MT; mi++) {
#pragma unroll
        for (int ni = 0; ni < NT; ni++) {
            const int col = cb + ni * 16;
#pragma unroll
            for (int r = 0; r < 4; r++) {
                const int row = rb + mi * 16 + r;
                const float v = acc[mi][ni][r];
                if constexpr (MODE == 0) {
                    ((u16*)C)[(size_t)row * N + col] = f2bf(v);
                } else {
                    if (oflag) ((u16*)C)[(size_t)row * N + col] = f2bf(v);
                    else       ((float*)C)[(size_t)row * N + col] = v;
                }
            }
        }
    }
}

// ---------------- generic bf16 MFMA GEMM:  C[M,N] = A[M,K] * Bt[N,K]^T -------
// (kept for K3's split-K atomic path)
template <int BM, int BN, int BK, int WR, int WC, int MT, int NT, int MODE>
__global__ __launch_bounds__(256) void gemm_bt(
    const u16* __restrict__ A, const u16* __restrict__ Bt,
    void* __restrict__ C, const u16* __restrict__ bias,
    const int* __restrict__ oflagp,
    int M, int N, int K)
{
    static_assert(BK == 32, "BK=32 (one 16x16x32 MFMA k-slab)");
    __shared__ u16 As[BM * BK];
    __shared__ u16 Bs[BN * BK];

    const int tid  = threadIdx.x;
    const int lane = tid & 63;
    const int wave = tid >> 6;
    const int wm = wave / WC, wn = wave % WC;

    const int m0 = blockIdx.y * BM;
    const int n0 = blockIdx.x * BN;
    const int Kchunk = K / gridDim.z;
    const int kbeg = blockIdx.z * Kchunk;
    const int kend = kbeg + Kchunk;

    f32x4 acc[MT][NT];
#pragma unroll
    for (int mi = 0; mi < MT; mi++)
#pragma unroll
        for (int ni = 0; ni < NT; ni++)
            acc[mi][ni] = (f32x4){0.f, 0.f, 0.f, 0.f};

    const int q = lane >> 4;               // k-quad this lane consumes
    const int arow = wm * MT * 16 + (lane & 15);
    const int brow = wn * NT * 16 + (lane & 15);

    constexpr int CHA = BM * 4;            // 16B chunks in A tile
    constexpr int CHB = BN * 4;

    for (int k0 = kbeg; k0 < kend; k0 += BK) {
        __syncthreads();
        // async stage A tile: chunk c holds global quad (c&3)^((row>>1)&3)
#pragma unroll
        for (int it = 0; it < (CHA + 255) / 256; it++) {
            const int c = it * 256 + tid;
            if (CHA % 256 == 0 || c < CHA) {
                const int row = c >> 2, kc = SWZ(row, c & 3);
                const u16* gp = &A[(size_t)(m0 + row) * K + k0 + kc * 8];
                __builtin_amdgcn_global_load_lds(
                    (const __attribute__((address_space(1))) void*)gp,
                    (__attribute__((address_space(3))) void*)&As[c * 8], 16, 0, 0);
            }
        }
#pragma unroll
        for (int it = 0; it < (CHB + 255) / 256; it++) {
            const int c = it * 256 + tid;
            if (CHB % 256 == 0 || c < CHB) {
                const int row = c >> 2, kc = SWZ(row, c & 3);
                const u16* gp = &Bt[(size_t)(n0 + row) * K + k0 + kc * 8];
                __builtin_amdgcn_global_load_lds(
                    (const __attribute__((address_space(1))) void*)gp,
                    (__attribute__((address_space(3))) void*)&Bs[c * 8], 16, 0, 0);
            }
        }
        __syncthreads();

        bf16x8 af[MT], bfr[NT];
#pragma unroll
        for (int mi = 0; mi < MT; mi++) {
            const int row = arow + mi * 16;
            af[mi] = *reinterpret_cast<const bf16x8*>(&As[row * BK + SWZ(row, q) * 8]);
        }
#pragma unroll
        for (int ni = 0; ni < NT; ni++) {
            const int row = brow + ni * 16;
            bfr[ni] = *reinterpret_cast<const bf16x8*>(&Bs[row * BK + SWZ(row, q) * 8]);
        }
#pragma unroll
        for (int mi = 0; mi < MT; mi++)
#pragma unroll
            for (int ni = 0; ni < NT; ni++)
                acc[mi][ni] = __builtin_amdgcn_mfma_f32_16x16x32_bf16(
                    af[mi], bfr[ni], acc[mi][ni], 0, 0, 0);
    }

    const int rb = m0 + wm * MT * 16 + ((lane >> 4) << 2);
    const int cb = n0 + wn * NT * 16 + (lane & 15);
#pragma unroll
    for (int mi = 0; mi < MT; mi++) {
#pragma unroll
        for (int ni = 0; ni < NT; ni++) {
            const int col = cb + ni * 16;
#pragma unroll
            for (int r = 0; r < 4; r++) {
                const int row = rb + mi * 16 + r;
                const float v = acc[mi][ni][r];
                if constexpr (MODE == 0) {
                    ((u16*)C)[(size_t)row * N + col] = f2bf(v);
                } else if constexpr (MODE == 4) {
                    atomicAdd(((float*)C) + (size_t)row * N + col, v);
                }
            }
        }
    }
}

// ---------------- dedicated dt GEMM: dt = softplus(dtin @ W_dtT^T + b) ------
// M=2048, N=4096, K=128 (whole K staged once). 64x64 tile, 2048 blocks.
// Epilogue: acc -> LDS fp32 [64][68] -> float4 coalesced global stores.
__global__ __launch_bounds__(256) void dt_gemm(
    const u16* __restrict__ A,      // dtin  [2048 x 128] bf16
    const u16* __restrict__ Bt,     // W_dtT [4096 x 128] bf16
    float* __restrict__ C,          // dtv   [2048 x 4096] fp32
    const u16* __restrict__ bias)   // b_dt  [4096] bf16
{
    __shared__ ulong4 smem_raw[2048];            // 32 KB
    u16* As = (u16*)smem_raw;                    // [64][128] swizzled bf16
    u16* Bs = As + 64 * 128;                     // [64][128] swizzled bf16
    float* Cs = (float*)smem_raw;                // [64][68] fp32 (aliases As/Bs)

    const int tid  = threadIdx.x;
    const int lane = tid & 63;
    const int wave = tid >> 6;
    const int n0 = blockIdx.x * 64;
    const int m0 = blockIdx.y * 64;

    // stage A and B tiles: 64 rows x 16 chunks (16 B) each, 4 iters x 256 thr.
#pragma unroll
    for (int it = 0; it < 4; it++) {
        const int c = it * 256 + tid;
        const int row = c >> 4, cc = (c & 15) ^ (row & 7);
        const u16* gp = &A[(size_t)(m0 + row) * 128 + cc * 8];
        __builtin_amdgcn_global_load_lds(
            (const __attribute__((address_space(1))) void*)gp,
            (__attribute__((address_space(3))) void*)&As[c * 8], 16, 0, 0);
    }
#pragma unroll
    for (int it = 0; it < 4; it++) {
        const int c = it * 256 + tid;
        const int row = c >> 4, cc = (c & 15) ^ (row & 7);
        const u16* gp = &Bt[(size_t)(n0 + row) * 128 + cc * 8];
        __builtin_amdgcn_global_load_lds(
            (const __attribute__((address_space(1))) void*)gp,
            (__attribute__((address_space(3))) void*)&Bs[c * 8], 16, 0, 0);
    }
    __syncthreads();

    // wave w owns rows m0 + w*16 .. +15, all 64 cols of the tile.
    const int q  = lane >> 4;                 // k-quad this lane consumes
    const int ar = wave * 16 + (lane & 15);   // A row within tile
    f32x4 acc[4];
#pragma unroll
    for (int ni = 0; ni < 4; ni++) acc[ni] = (f32x4){0.f, 0.f, 0.f, 0.f};

#pragma unroll
    for (int kk = 0; kk < 4; kk++) {          // 4 k-slabs of 32
        const int cA = kk * 4 + q;            // 16B chunk index within row
        const bf16x8 af = *reinterpret_cast<const bf16x8*>(
            &As[(ar * 16 + (cA ^ (ar & 7))) * 8]);
#pragma unroll
        for (int ni = 0; ni < 4; ni++) {
            const int br = ni * 16 + (lane & 15);
            const bf16x8 bfr = *reinterpret_cast<const bf16x8*>(
                &Bs[(br * 16 + (cA ^ (br & 7))) * 8]);
            acc[ni] = __builtin_amdgcn_mfma_f32_16x16x32_bf16(af, bfr, acc[ni], 0, 0, 0);
        }
    }
    __syncthreads();   // all As/Bs reads done before Cs overwrites them

    // fragment -> LDS fp32 tile (stride 68 breaks the 256B bank aliasing)
#pragma unroll
    for (int ni = 0; ni < 4; ni++) {
        const int col = ni * 16 + (lane & 15);
#pragma unroll
        for (int r = 0; r < 4; r++) {
            const int rowl = wave * 16 + q * 4 + r;
            Cs[rowl * 68 + col] = acc[ni][r];
        }
    }
    __syncthreads();

    // LDS -> global: 4 passes x float4 per thread; bias + softplus fused.
#pragma unroll
    for (int p = 0; p < 4; p++) {
        const int rowl = p * 16 + (tid >> 4);
        const int c0 = (tid & 15) * 4;
        float4 v = *reinterpret_cast<const float4*>(&Cs[rowl * 68 + c0]);
        float* vp = reinterpret_cast<float*>(&v);
#pragma unroll
        for (int j = 0; j < 4; j++) {
            const float x = vp[j] + bf2f(bias[n0 + c0 + j]);
            // softplus(x) = max(x,0) + log1p(exp(-|x|)); fast hw exp/log
            vp[j] = fmaxf(x, 0.f) + __logf(1.f + __expf(-fabsf(x)));
        }
        *reinterpret_cast<float4*>(&C[(size_t)(m0 + rowl) * 4096 + n0 + c0]) = v;
    }
}

// ---------------- depthwise conv3 + bias + silu (8 ch/thread) ---------------
__global__ void conv_silu(const u16* __restrict__ xz, const u16* __restrict__ conv_w,
                          const u16* __restrict__ conv_b, u16* __restrict__ xc) {
    const int idx = blockIdx.x * 256 + threadIdx.x;    // 2048*512 threads
    const int row = idx >> 9, c0 = (idx & 511) * 8;
    const int l = row & 1023;

    u16 wcat[24];
    *(u16x8*)&wcat[0]  = *(const u16x8*)&conv_w[c0 * 3];
    *(u16x8*)&wcat[8]  = *(const u16x8*)&conv_w[c0 * 3 + 8];
    *(u16x8*)&wcat[16] = *(const u16x8*)&conv_w[c0 * 3 + 16];
    const u16x8 bv = *(const u16x8*)&conv_b[c0];
    const u16x8 x0 = *(const u16x8*)&xz[(size_t)row * 8192 + c0];
    u16x8 xm = {}, xp = {};
    if (l > 0)    xm = *(const u16x8*)&xz[(size_t)(row - 1) * 8192 + c0];
    if (l < 1023) xp = *(const u16x8*)&xz[(size_t)(row + 1) * 8192 + c0];

    u16x8 out;
#pragma unroll
    for (int i = 0; i < 8; i++) {
        float v = bf2f(wcat[3 * i]) * bf2f(xm[i])
                + bf2f(wcat[3 * i + 1]) * bf2f(x0[i])
                + bf2f(wcat[3 * i + 2]) * bf2f(xp[i])
                + bf2f(bv[i]);
        v = v / (1.f + __expf(-v));
        out[i] = f2bf(v);
    }
    *(u16x8*)&xc[(size_t)row * 4096 + c0] = out;
}

// ---------------- x_dbl[:, :128] -> bf16 ------------------------------------
__global__ void cvt_dtin(const float* __restrict__ x_dbl, u16* __restrict__ dtin) {
    const int idx = blockIdx.x * 256 + threadIdx.x;    // 2048*128
    const int row = idx >> 7, c = idx & 127;
    dtin[idx] = f2bf(x_dbl[(size_t)row * 160 + c]);
}

// ---------------- S1: per-chunk local scan (h_in = 0), lane = channel -------
// grid (NCHUNK, 16, 2), 256 threads: lane owns all 16 states of one channel.
__global__ __launch_bounds__(256) void scan_p1(
    const float* __restrict__ dt, const u16* __restrict__ xc,
    const float* __restrict__ x_dbl, const u16* __restrict__ A_log,
    float* __restrict__ Parr, u16* __restrict__ xzbase)
{
    __shared__ float Bsm[CLEN][16];
    const int tid = threadIdx.x;
    const int nc = blockIdx.x, cg = blockIdx.y, b = blockIdx.z;
    const int ch = cg * 256 + tid;
    const size_t row0 = (size_t)b * 1024 + nc * CLEN;

    {   // stage B[t][s]: 64 rows x 16 floats; 256 threads x 1 float4
        const int t = tid >> 2, q = tid & 3;
        const float4 v = *(const float4*)&x_dbl[(row0 + t) * 160 + 128 + q * 4];
        *(float4*)&Bsm[t][q * 4] = v;
    }
    __syncthreads();

    float A_s[16], h[16];
#pragma unroll
    for (int s = 0; s < 16; s++) {
        A_s[s] = -__expf(bf2f(A_log[ch * 16 + s]));
        h[s] = 0.f;
    }
    float Sdt = 0.f;

    float dt_v = dt[row0 * 4096 + ch];
    float u_v  = bf2f(xc[row0 * 4096 + ch]);
    for (int t = 0; t < CLEN; t++) {
        const int tn = (t + 1 < CLEN) ? t + 1 : t;
        const float dt_n = dt[(row0 + tn) * 4096 + ch];
        const float u_n  = bf2f(xc[(row0 + tn) * 4096 + ch]);
        const float dtu = dt_v * u_v;
        Sdt += dt_v;
        const f32x4* Brow = (const f32x4*)&Bsm[t][0];
        const f32x4 B0 = Brow[0], B1 = Brow[1], B2 = Brow[2], B3 = Brow[3];
#pragma unroll
        for (int s = 0; s < 16; s++) {
            const float Bs_ = (s < 4 ? B0[s & 3] : s < 8 ? B1[s & 3] : s < 12 ? B2[s & 3] : B3[s & 3]);
            const float dA = __expf(dt_v * A_s[s]);
            h[s] = dA * h[s] + dtu * Bs_;
        }
        dt_v = dt_n; u_v = u_n;
    }
    const int i0 = (((b * NCHUNK + nc) * 4096) + ch) * 16;
    float* pp = &Parr[i0];
    float* hp = hloc_ptr(xzbase, i0);
#pragma unroll
    for (int s4 = 0; s4 < 4; s4++) {
        float4 pq, hq;
        pq.x = __expf(A_s[4 * s4 + 0] * Sdt);
        pq.y = __expf(A_s[4 * s4 + 1] * Sdt);
        pq.z = __expf(A_s[4 * s4 + 2] * Sdt);
        pq.w = __expf(A_s[4 * s4 + 3] * Sdt);
        hq.x = h[4 * s4 + 0]; hq.y = h[4 * s4 + 1];
        hq.z = h[4 * s4 + 2]; hq.w = h[4 * s4 + 3];
        *(float4*)&pp[4 * s4] = pq;
        *(float4*)&hp[4 * s4] = hq;
    }
}

// ---------------- S2: combine chunk summaries -> h_in -----------------------
__global__ __launch_bounds__(256) void scan_p2(
    const float* __restrict__ Parr, u16* __restrict__ xzbase)
{
    const int tid = threadIdx.x;
    const int lane = tid & 63, wave = tid >> 6;
    const int blk = blockIdx.x;
    const int b = blk >> 8, cg = blk & 255;
    const int c_local = lane & 3, s = lane >> 2;
    const int ch = cg * 16 + wave * 4 + c_local;

    float Pv[NCHUNK], hl[NCHUNK];
#pragma unroll
    for (int c = 0; c < NCHUNK; c++) {
        const int i = (((b * NCHUNK + c) * 4096) + ch) * 16 + s;
        Pv[c] = Parr[i];
        hl[c] = *hloc_ptr(xzbase, i);
    }
    float hin = 0.f;
#pragma unroll
    for (int c = 0; c < NCHUNK; c++) {
        const int i = (((b * NCHUNK + c) * 4096) + ch) * 16 + s;
        *hin_ptr(xzbase, i) = hin;
        hin = Pv[c] * hin + hl[c];
    }
}

// ---------------- S3: rescan with h_in; fused gate; lane = channel ----------
__global__ __launch_bounds__(256) void scan_p3(
    const float* __restrict__ dt, const u16* __restrict__ xc,
    const float* __restrict__ x_dbl, const u16* __restrict__ xz,
    const u16* __restrict__ A_log, const u16* __restrict__ Dp,
    u16* __restrict__ yg, u16* __restrict__ xzbase)
{
    __shared__ float BCs[CLEN][32];   // [t][0..15]=B, [t][16..31]=C
    const int tid = threadIdx.x;
    const int nc = blockIdx.x, cg = blockIdx.y, b = blockIdx.z;
    const int ch = cg * 256 + tid;
    const size_t row0 = (size_t)b * 1024 + nc * CLEN;

#pragma unroll
    for (int it = 0; it < 2; it++) {   // 64 rows x 32 floats; 512 float4
        const int c = it * 256 + tid;
        const int t = c >> 3, q = c & 7;
        const float4 v = *(const float4*)&x_dbl[(row0 + t) * 160 + 128 + q * 4];
        *(float4*)&BCs[t][q * 4] = v;
    }
    __syncthreads();

    float A_s[16], h[16];
    const int i0 = (((b * NCHUNK + nc) * 4096) + ch) * 16;
    {
        const float* hp = hin_ptr(xzbase, i0);
#pragma unroll
        for (int s4 = 0; s4 < 4; s4++) {
            const float4 hq = *(const float4*)&hp[4 * s4];
            h[4 * s4 + 0] = hq.x; h[4 * s4 + 1] = hq.y;
            h[4 * s4 + 2] = hq.z; h[4 * s4 + 3] = hq.w;
        }
    }
#pragma unroll
    for (int s = 0; s < 16; s++)
        A_s[s] = -__expf(bf2f(A_log[ch * 16 + s]));
    const float D_ch = bf2f(Dp[ch]);

    float dt_v = dt[row0 * 4096 + ch];
    float u_v  = bf2f(xc[row0 * 4096 + ch]);
    float z_v  = bf2f(xz[row0 * 8192 + 4096 + ch]);
    for (int t = 0; t < CLEN; t++) {
        const int tn = (t + 1 < CLEN) ? t + 1 : t;
        const size_t rn = row0 + tn;
        const float dt_n = dt[rn * 4096 + ch];
        const float u_n  = bf2f(xc[rn * 4096 + ch]);
        const float z_n  = bf2f(xz[rn * 8192 + 4096 + ch]);
        const float dtu = dt_v * u_v;

        const f32x4* Row = (const f32x4*)&BCs[t][0];
        const f32x4 B0 = Row[0], B1 = Row[1], B2 = Row[2], B3 = Row[3];
        const f32x4 C0 = Row[4], C1 = Row[5], C2 = Row[6], C3 = Row[7];

        float y0 = 0.f, y1 = 0.f, y2 = 0.f, y3 = 0.f;
#pragma unroll
        for (int s = 0; s < 16; s++) {
            const float Bs_ = (s < 4 ? B0[s & 3] : s < 8 ? B1[s & 3] : s < 12 ? B2[s & 3] : B3[s & 3]);
            const float Cs_ = (s < 4 ? C0[s & 3] : s < 8 ? C1[s & 3] : s < 12 ? C2[s & 3] : C3[s & 3]);
            const float dA = __expf(dt_v * A_s[s]);
            h[s] = dA * h[s] + dtu * Bs_;
            const float hc = h[s] * Cs_;
            if ((s & 3) == 0) y0 += hc; else if ((s & 3) == 1) y1 += hc;
            else if ((s & 3) == 2) y2 += hc; else y3 += hc;
        }
        const float y = (y0 + y1) + (y2 + y3);
        const float silu_z = z_v / (1.f + __expf(-z_v));
        yg[(row0 + t) * 4096 + ch] = f2bf((y + u_v * D_ch) * silu_z);
        dt_v = dt_n; u_v = u_n; z_v = z_n;
    }
}

extern "C" void kernel_launch(void* const* d_in, const int* in_sizes, int n_in,
                              void* d_out, int out_size, void* d_ws, size_t ws_size,
                              hipStream_t stream)
{
    const void* x_raw      = d_in[0];   // (2,1024,2048)
    const void* W_in_raw   = d_in[1];   // (2048,8192)
    const void* conv_w_raw = d_in[2];   // (4096,1,3)
    const void* conv_b_raw = d_in[3];   // (4096)
    const void* W_x_raw    = d_in[4];   // (4096,160)
    const void* W_dt_raw   = d_in[5];   // (128,4096)
    const void* b_dt_raw   = d_in[6];   // (4096)
    const void* A_log_raw  = d_in[7];   // (4096,16)
    const void* D_raw      = d_in[8];   // (4096)
    const void* W_out_raw  = d_in[9];   // (4096,2048)

    char* ws = (char*)d_ws;
    size_t off = 0;
    auto alloc = [&](size_t bytes) { char* p = ws + off; off += (bytes + 255) & ~(size_t)255; return p; };
    int*   flag   = (int*)  alloc(4);
    u16*   W_inT  = (u16*)  alloc(8192ULL * 2048 * 2);   // 32 MB (aliased by dt fp32 after K1)
    u16*   W_outT = (u16*)  alloc(2048ULL * 4096 * 2);   // 16 MB
    u16*   W_dtT  = (u16*)  alloc(4096ULL * 128 * 2);    // 1 MB
    u16*   W_xT   = (u16*)  alloc(160ULL * 4096 * 2);    // 1.25 MB
    u16*   xz     = (u16*)  alloc(2048ULL * 8192 * 2);   // 32 MB (xp half reused as h_loc/h_in)
    u16*   xc     = (u16*)  alloc(2048ULL * 4096 * 2);   // 16 MB
    float* x_dbl  = (float*)alloc(2048ULL * 160 * 4);    // 1.25 MB
    u16*   dtin   = (u16*)  alloc(2048ULL * 128 * 2);    // 0.5 MB
    u16*   yg     = (u16*)  alloc(2048ULL * 4096 * 2);   // 16 MB
    u16*   xcan   = (u16*)  alloc(2048ULL * 2048 * 2);   // 8 MB (reused as Parr fp32)
    u16*   cw_c   = (u16*)  alloc(12288 * 2);
    u16*   cb_c   = (u16*)  alloc(4096 * 2);
    u16*   bdt_c  = (u16*)  alloc(4096 * 2);
    u16*   Alog_c = (u16*)  alloc(65536 * 2);
    u16*   D_c    = (u16*)  alloc(4096 * 2);
    float* dtv    = (float*)W_inT;   // alias: W_inT dead after K1 (32 MB exact)
    float* Parr   = (float*)xcan;    // alias: xcan dead after K1 (8 MB exact)

    // D) dtype flag, fused canonicalize + x_dbl zero
    detect_dtype<<<1, 256, 0, stream>>>((const u16*)x_raw, flag);
    cvt_fused<<<16384 + 48 + 16 + 16 + 256 + 16 + 1280, 256, 0, stream>>>(
        x_raw, xcan, conv_w_raw, cw_c, conv_b_raw, cb_c, b_dt_raw, bdt_c,
        A_log_raw, Alog_c, D_raw, D_c, x_dbl, flag);

    // T) fused transposes (64x32 tiles, u32 writes)
    transpose_fused<<<8192 + 4096 + 256 + 320, dim3(32, 8), 0, stream>>>(
        W_in_raw, W_inT, W_out_raw, W_outT, W_dt_raw, W_dtT, W_x_raw, W_xT, flag);

    // K1: xz = x @ W_in   (M=2048, N=8192, K=2048), 256^2 ring-4 2-phase
    (void)hipFuncSetAttribute(
        reinterpret_cast<const void*>(&gemm_ring<256, 256, 2, 4, 0>),
        hipFuncAttributeMaxDynamicSharedMemorySize, 131072);
    gemm_ring<256, 256, 2, 4, 0><<<dim3(8192 / 256, 2048 / 256), 512, 131072, stream>>>(
        xcan, W_inT, xz, nullptr, 2048, 8192, 2048);

    // K2: conv + bias + silu (8 ch/thread)
    conv_silu<<<(2048 * 512) / 256, 256, 0, stream>>>(xz, cw_c, cb_c, xc);

    // K3: x_dbl = xc @ W_x   (split-K=8, atomic fp32; x_dbl zeroed in cvt_fused)
    gemm_bt<64, 160, 32, 4, 1, 1, 10, 4>
        <<<dim3(1, 2048 / 64, 8), 256, 0, stream>>>(xc, W_xT, x_dbl, nullptr, nullptr, 2048, 160, 4096);

    cvt_dtin<<<(2048 * 128) / 256, 256, 0, stream>>>(x_dbl, dtin);

    // K4: dt = softplus(dtin @ W_dt + b_dt)   (fp32 out, dedicated kernel)
    dt_gemm<<<dim3(4096 / 64, 2048 / 64), 256, 0, stream>>>(dtin, W_dtT, dtv, bdt_c);

    // S1/S2/S3: chunked selective scan (lane=channel) with fused gating
    scan_p1<<<dim3(NCHUNK, 16, 2), 256, 0, stream>>>(dtv, xc, x_dbl, Alog_c, Parr, xz);
    scan_p2<<<512, 256, 0, stream>>>(Parr, xz);
    scan_p3<<<dim3(NCHUNK, 16, 2), 256, 0, stream>>>(dtv, xc, x_dbl, xz, Alog_c, D_c, yg, xz);

    // K6: out = yg @ W_out   (M=2048, N=2048, K=4096), 128^2 ring-4 2-phase
    (void)hipFuncSetAttribute(
        reinterpret_cast<const void*>(&gemm_ring<128, 128, 2, 2, 1>),
        hipFuncAttributeMaxDynamicSharedMemorySize, 65536);
    gemm_ring<128, 128, 2, 2, 1><<<dim3(2048 / 128, 2048 / 128), 256, 65536, stream>>>(
        yg, W_outT, d_out, flag, 2048, 2048, 4096);
}

// Round 7
// 408.802 us; speedup vs baseline: 1.0980x; 1.0524x over previous
//
#include <hip/hip_runtime.h>
#include <hip/hip_bf16.h>

// Selective SSM (Mamba-style): B=2, L=1024, H=2048, E=2 -> d=4096, S=16, R=128.
// Round 14: tail batch #2 (GEMM schedules untouched).
// (a) K3: split-K atomics (2.6M scattered fp32 atomicAdd) -> MODE-5 partials
//     + reduce_xdbl kernel that also emits dtin bf16 (cvt_dtin deleted, x_dbl
//     zeroing deleted). (b) cvt_fused x-path vectorized x8 (16384->2048 blks).
// (c) transpose_fused reads vectorized to u16x2/float2 ([64][34] tile).

using u16 = unsigned short;
typedef __bf16 bf16x8 __attribute__((ext_vector_type(8)));
typedef float f32x4 __attribute__((ext_vector_type(4)));
typedef u16 u16x8 __attribute__((ext_vector_type(8)));

#define NCHUNK 16
#define CLEN   64
// chunk swizzle: quad j of row r lives at chunk r*4 + (j ^ ((r>>1)&3))
#define SWZ(row, q) ((q) ^ (((row) >> 1) & 3))

__device__ __forceinline__ float bf2f(u16 u) {
    union { unsigned int i; float f; } v; v.i = ((unsigned int)u) << 16; return v.f;
}
__device__ __forceinline__ u16 f2bf(float f) {
    union { float f; unsigned int i; } v; v.f = f;
    unsigned int x = v.i;
    return (u16)((x + 0x7FFFu + ((x >> 16) & 1u)) >> 16);   // RNE
}

// fp32 scratch carved out of the dead xp-column half of xz (rows x 8192 u16;
// cols 0..4095 dead after conv). h_loc: rows 0..1023, h_in: rows 1024..2047.
__device__ __forceinline__ float* hloc_ptr(u16* xzbase, int i) {
    return reinterpret_cast<float*>(xzbase + (size_t)(i >> 11) * 8192) + (i & 2047);
}
__device__ __forceinline__ float* hin_ptr(u16* xzbase, int i) {
    return reinterpret_cast<float*>(xzbase + (size_t)((i >> 11) + 1024) * 8192) + (i & 2047);
}

// ---------------- dtype detection -------------------------------------------
__global__ void detect_dtype(const u16* __restrict__ xraw, int* __restrict__ flag) {
    __shared__ int cnt[256];
    const int tid = threadIdx.x;
    int plausible = 0;
    for (int i = tid; i < 4096; i += 256) {
        const u16 v = xraw[2 * i];
        const int e = (v >> 7) & 0xFF;
        plausible += (e >= 100 && e <= 145) ? 1 : 0;
    }
    cnt[tid] = plausible;
    __syncthreads();
    for (int s = 128; s > 0; s >>= 1) {
        if (tid < s) cnt[tid] += cnt[tid + s];
        __syncthreads();
    }
    if (tid == 0) *flag = (cnt[0] > 2458) ? 1 : 0;
}

// ---------------- fused canonicalize (6 tensors), 8 elems/thread ------------
__device__ __forceinline__ void cvt_seg8(const void* src, u16* dst, int i8,
                                         bool isbf) {
    if (isbf) {
        *(u16x8*)&dst[i8 * 8] = *((const u16x8*)src + i8);
    } else {
        const float* f = (const float*)src + i8 * 8;
        u16x8 o;
#pragma unroll
        for (int j = 0; j < 8; j++) o[j] = f2bf(f[j]);
        *(u16x8*)&dst[i8 * 8] = o;
    }
}
__global__ void cvt_fused(const void* __restrict__ x_raw, u16* __restrict__ xcan,
                          const void* __restrict__ cw_raw, u16* __restrict__ cw_c,
                          const void* __restrict__ cb_raw, u16* __restrict__ cb_c,
                          const void* __restrict__ bdt_raw, u16* __restrict__ bdt_c,
                          const void* __restrict__ Alog_raw, u16* __restrict__ Alog_c,
                          const void* __restrict__ D_raw, u16* __restrict__ D_c,
                          const int* __restrict__ flag) {
    const bool isbf = (*flag != 0);
    int blk = blockIdx.x;
    const int tid = threadIdx.x;
    if (blk < 2048) { cvt_seg8(x_raw, xcan, blk * 256 + tid, isbf); return; }   // 4.19M
    blk -= 2048;
    if (blk < 6)  { cvt_seg8(cw_raw, cw_c, blk * 256 + tid, isbf); return; }    // 12288
    blk -= 6;
    if (blk < 2)  { cvt_seg8(cb_raw, cb_c, blk * 256 + tid, isbf); return; }    // 4096
    blk -= 2;
    if (blk < 2)  { cvt_seg8(bdt_raw, bdt_c, blk * 256 + tid, isbf); return; }  // 4096
    blk -= 2;
    if (blk < 32) { cvt_seg8(Alog_raw, Alog_c, blk * 256 + tid, isbf); return; }// 65536
    blk -= 32;
    cvt_seg8(D_raw, D_c, blk * 256 + tid, isbf);                                 // 4096
}

// ---------------- fused flag-aware transposes (4 tensors) -------------------
// 64(rows) x 32(cols) input tile; u16x2/float2 reads; u32 transposed writes.
__device__ __forceinline__ void tr_tile(const void* in, u16* out, int R, int C,
                                        int bx, int by, int tx, int ty, bool isbf,
                                        u16 (*tile)[34]) {
    const int c0 = bx * 32, r0 = by * 64;
    const int cp = tx & 15, rh = tx >> 4;      // colpair 0..15, row-half 0/1
#pragma unroll
    for (int i = 0; i < 4; i++) {
        const int row = ty + rh * 8 + i * 16;
        const size_t idx = (size_t)(r0 + row) * C + c0 + cp * 2;
        if (isbf) {
            union { unsigned int u; u16 h[2]; } p;
            p.u = *reinterpret_cast<const unsigned int*>(&((const u16*)in)[idx]);
            tile[row][cp * 2] = p.h[0];
            tile[row][cp * 2 + 1] = p.h[1];
        } else {
            const float2 f = *reinterpret_cast<const float2*>(&((const float*)in)[idx]);
            tile[row][cp * 2] = f2bf(f.x);
            tile[row][cp * 2 + 1] = f2bf(f.y);
        }
    }
    __syncthreads();
#pragma unroll
    for (int i = 0; i < 4; i++) {
        const int w = ty + i * 8;                       // output row-local 0..31
        union { u16 h[2]; unsigned int u; } p;
        p.h[0] = tile[2 * tx][w];
        p.h[1] = tile[2 * tx + 1][w];
        *reinterpret_cast<unsigned int*>(&out[(size_t)(c0 + w) * R + r0 + 2 * tx]) = p.u;
    }
}
__global__ void transpose_fused(const void* __restrict__ Wi, u16* __restrict__ WiT,
                                const void* __restrict__ Wo, u16* __restrict__ WoT,
                                const void* __restrict__ Wd, u16* __restrict__ WdT,
                                const void* __restrict__ Wx, u16* __restrict__ WxT,
                                const int* __restrict__ flag) {
    __shared__ u16 tile[64][34];
    const bool isbf = (*flag != 0);
    const int tx = threadIdx.x, ty = threadIdx.y;   // (32,8)
    int blk = blockIdx.x;
    if (blk < 8192) { tr_tile(Wi, WiT, 2048, 8192, blk % 256, blk / 256, tx, ty, isbf, tile); return; }
    blk -= 8192;
    if (blk < 4096) { tr_tile(Wo, WoT, 4096, 2048, blk % 64, blk / 64, tx, ty, isbf, tile); return; }
    blk -= 4096;
    if (blk < 256)  { tr_tile(Wd, WdT, 128, 4096, blk % 128, blk / 128, tx, ty, isbf, tile); return; }
    blk -= 256;
    tr_tile(Wx, WxT, 4096, 160, blk % 5, blk / 5, tx, ty, isbf, tile);   // 320 blocks
}

// ---------------- ring-4 deep-pipelined bf16 GEMM (2-phase K-step) ----------
// C[M,N] = A[M,K] * Bt[N,K]^T. 64*WM*WN threads; per-wave output
// (BM/WM) x (BN/WN). BK=32; LDS ring of 4 tile-buffers; staging runs 3 tiles
// ahead; per-tile s_waitcnt vmcnt(12) retires only the tile about to be
// consumed (4 loads/thread/stage in all instantiations). Raw s_barrier (no
// __syncthreads) so the compiler cannot force a vmcnt(0) drain.
// Compute split into NPH=2 phases of 16 MFMA with setprio around the cluster.
// Ring-4 WAR safety: tile t+3 overwrites buf[(t-1)&3], whose reads finished
// at iteration t-1's final phase barrier. Requires K>=96, K%32==0,
// M%BM==0, N%BN==0.
template <int BM, int BN, int THR>
__device__ __forceinline__ void stage_ring(const u16* __restrict__ Ab,
                                           const u16* __restrict__ Bb,
                                           int K, int k0, u16* dst, int tid)
{
    constexpr int CHA = BM * 4, CHB = BN * 4;
    static_assert(CHA % THR == 0 && CHB % THR == 0, "chunk/thread mismatch");
#pragma unroll
    for (int it = 0; it < CHA / THR; it++) {
        const int c = it * THR + tid;
        const int row = c >> 2, kc = SWZ(row, c & 3);
        __builtin_amdgcn_global_load_lds(
            (const __attribute__((address_space(1))) void*)(Ab + (size_t)row * K + k0 + kc * 8),
            (__attribute__((address_space(3))) void*)(dst + c * 8), 16, 0, 0);
    }
#pragma unroll
    for (int it = 0; it < CHB / THR; it++) {
        const int c = it * THR + tid;
        const int row = c >> 2, kc = SWZ(row, c & 3);
        __builtin_amdgcn_global_load_lds(
            (const __attribute__((address_space(1))) void*)(Bb + (size_t)row * K + k0 + kc * 8),
            (__attribute__((address_space(3))) void*)(dst + BM * 32 + c * 8), 16, 0, 0);
    }
}

template <int BM, int BN, int WM, int WN, int MODE>
__global__ __launch_bounds__(64 * WM * WN, 2) void gemm_ring(
    const u16* __restrict__ A, const u16* __restrict__ Bt, void* __restrict__ C,
    const int* __restrict__ oflagp, int M, int N, int K)
{
    constexpr int THR = 64 * WM * WN;
    constexpr int MT  = BM / (WM * 16);
    constexpr int NT  = BN / (WN * 16);
    constexpr int NPH = 2;                       // compute phases per K-tile
    constexpr int GM  = MT / NPH;                // mi-rows per phase
    constexpr int STG = (BM + BN) * 32;          // u16 per ring stage
    static_assert((BM * 4 + BN * 4) / THR == 4, "vmcnt ladder assumes 4 loads/thread/stage");
    static_assert(MT % NPH == 0, "MT must split into NPH phases");
    extern __shared__ u16 smem[];                // 4 * STG u16

    const int tid  = threadIdx.x;
    const int lane = tid & 63;
    const int wave = tid >> 6;
    const int wm = wave / WN, wn = wave % WN;
    const int q  = lane >> 4;                    // k-quad this lane consumes
    const int n0 = blockIdx.x * BN;
    const int m0 = blockIdx.y * BM;
    const int NTILE = K >> 5;                    // BK=32 tiles

    const u16* Ab = A  + (size_t)m0 * K;
    const u16* Bb = Bt + (size_t)n0 * K;

    // prologue: tiles 0..2 in flight (12 loads/thread)
    stage_ring<BM, BN, THR>(Ab, Bb, K, 0,  smem + 0 * STG, tid);
    stage_ring<BM, BN, THR>(Ab, Bb, K, 32, smem + 1 * STG, tid);
    stage_ring<BM, BN, THR>(Ab, Bb, K, 64, smem + 2 * STG, tid);

    f32x4 acc[MT][NT];
#pragma unroll
    for (int mi = 0; mi < MT; mi++)
#pragma unroll
        for (int ni = 0; ni < NT; ni++)
            acc[mi][ni] = (f32x4){0.f, 0.f, 0.f, 0.f};

    const int arow = wm * (MT * 16) + (lane & 15);
    const int brow = wn * (NT * 16) + (lane & 15);

    for (int t = 0; t < NTILE; t++) {
        const int tp = t + 3;
        if (tp < NTILE) {
            stage_ring<BM, BN, THR>(Ab, Bb, K, tp * 32, smem + (tp & 3) * STG, tid);
            asm volatile("s_waitcnt vmcnt(12)" ::: "memory");   // tile t landed
        } else if (tp == NTILE) {
            asm volatile("s_waitcnt vmcnt(8)" ::: "memory");
        } else if (tp == NTILE + 1) {
            asm volatile("s_waitcnt vmcnt(4)" ::: "memory");
        } else {
            asm volatile("s_waitcnt vmcnt(0)" ::: "memory");
        }
        __builtin_amdgcn_s_barrier();            // tile t visible to all

        const u16* As = smem + (t & 3) * STG;
        const u16* Bs = As + BM * 32;
        bf16x8 bfr[NT];
#pragma unroll
        for (int ni = 0; ni < NT; ni++) {
            const int r = brow + ni * 16;
            bfr[ni] = *reinterpret_cast<const bf16x8*>(&Bs[r * 32 + SWZ(r, q) * 8]);
        }
#pragma unroll
        for (int g = 0; g < NPH; g++) {
            bf16x8 af[GM];
#pragma unroll
            for (int i = 0; i < GM; i++) {
                const int r = arow + (g * GM + i) * 16;
                af[i] = *reinterpret_cast<const bf16x8*>(&As[r * 32 + SWZ(r, q) * 8]);
            }
            __builtin_amdgcn_s_setprio(1);
#pragma unroll
            for (int i = 0; i < GM; i++)
#pragma unroll
                for (int ni = 0; ni < NT; ni++)
                    acc[g * GM + i][ni] = __builtin_amdgcn_mfma_f32_16x16x32_bf16(
                        af[i], bfr[ni], acc[g * GM + i][ni], 0, 0, 0);
            __builtin_amdgcn_s_setprio(0);
            __builtin_amdgcn_sched_barrier(0);   // pin phase reads before barrier
            __builtin_amdgcn_s_barrier();        // phase boundary (last = exit)
        }
    }

    int oflag = 1;
    if constexpr (MODE == 1) oflag = *oflagp;    // after loop: vmcnt already 0

    const int rb = m0 + wm * (MT * 16) + (q << 2);
    const int cb = n0 + wn * (NT * 16) + (lane & 15);
#pragma unroll
    for (int mi = 0; mi < MT; mi++) {
#pragma unroll
        for (int ni = 0; ni < NT; ni++) {
            const int col = cb + ni * 16;
#pragma unroll
            for (int r = 0; r < 4; r++) {
                const int row = rb + mi * 16 + r;
                const float v = acc[mi][ni][r];
                if constexpr (MODE == 0) {
                    ((u16*)C)[(size_t)row * N + col] = f2bf(v);
                } else {
                    if (oflag) ((u16*)C)[(size_t)row * N + col] = f2bf(v);
                    else       ((float*)C)[(size_t)row * N + col] = v;
                }
            }
        }
    }
}

// ---------------- generic bf16 MFMA GEMM:  C[M,N] = A[M,K] * Bt[N,K]^T -------
// (kept for K3's split-K path; MODE 5 = per-z fp32 partial stores, no atomics)
template <int BM, int BN, int BK, int WR, int WC, int MT, int NT, int MODE>
__global__ __launch_bounds__(256) void gemm_bt(
    const u16* __restrict__ A, const u16* __restrict__ Bt,
    void* __restrict__ C, const u16* __restrict__ bias,
    const int* __restrict__ oflagp,
    int M, int N, int K)
{
    static_assert(BK == 32, "BK=32 (one 16x16x32 MFMA k-slab)");
    __shared__ u16 As[BM * BK];
    __shared__ u16 Bs[BN * BK];

    const int tid  = threadIdx.x;
    const int lane = tid & 63;
    const int wave = tid >> 6;
    const int wm = wave / WC, wn = wave % WC;

    const int m0 = blockIdx.y * BM;
    const int n0 = blockIdx.x * BN;
    const int Kchunk = K / gridDim.z;
    const int kbeg = blockIdx.z * Kchunk;
    const int kend = kbeg + Kchunk;

    f32x4 acc[MT][NT];
#pragma unroll
    for (int mi = 0; mi < MT; mi++)
#pragma unroll
        for (int ni = 0; ni < NT; ni++)
            acc[mi][ni] = (f32x4){0.f, 0.f, 0.f, 0.f};

    const int q = lane >> 4;               // k-quad this lane consumes
    const int arow = wm * MT * 16 + (lane & 15);
    const int brow = wn * NT * 16 + (lane & 15);

    constexpr int CHA = BM * 4;            // 16B chunks in A tile
    constexpr int CHB = BN * 4;

    for (int k0 = kbeg; k0 < kend; k0 += BK) {
        __syncthreads();
        // async stage A tile: chunk c holds global quad (c&3)^((row>>1)&3)
#pragma unroll
        for (int it = 0; it < (CHA + 255) / 256; it++) {
            const int c = it * 256 + tid;
            if (CHA % 256 == 0 || c < CHA) {
                const int row = c >> 2, kc = SWZ(row, c & 3);
                const u16* gp = &A[(size_t)(m0 + row) * K + k0 + kc * 8];
                __builtin_amdgcn_global_load_lds(
                    (const __attribute__((address_space(1))) void*)gp,
                    (__attribute__((address_space(3))) void*)&As[c * 8], 16, 0, 0);
            }
        }
#pragma unroll
        for (int it = 0; it < (CHB + 255) / 256; it++) {
            const int c = it * 256 + tid;
            if (CHB % 256 == 0 || c < CHB) {
                const int row = c >> 2, kc = SWZ(row, c & 3);
                const u16* gp = &Bt[(size_t)(n0 + row) * K + k0 + kc * 8];
                __builtin_amdgcn_global_load_lds(
                    (const __attribute__((address_space(1))) void*)gp,
                    (__attribute__((address_space(3))) void*)&Bs[c * 8], 16, 0, 0);
            }
        }
        __syncthreads();

        bf16x8 af[MT], bfr[NT];
#pragma unroll
        for (int mi = 0; mi < MT; mi++) {
            const int row = arow + mi * 16;
            af[mi] = *reinterpret_cast<const bf16x8*>(&As[row * BK + SWZ(row, q) * 8]);
        }
#pragma unroll
        for (int ni = 0; ni < NT; ni++) {
            const int row = brow + ni * 16;
            bfr[ni] = *reinterpret_cast<const bf16x8*>(&Bs[row * BK + SWZ(row, q) * 8]);
        }
#pragma unroll
        for (int mi = 0; mi < MT; mi++)
#pragma unroll
            for (int ni = 0; ni < NT; ni++)
                acc[mi][ni] = __builtin_amdgcn_mfma_f32_16x16x32_bf16(
                    af[mi], bfr[ni], acc[mi][ni], 0, 0, 0);
    }

    const int rb = m0 + wm * MT * 16 + ((lane >> 4) << 2);
    const int cb = n0 + wn * NT * 16 + (lane & 15);
#pragma unroll
    for (int mi = 0; mi < MT; mi++) {
#pragma unroll
        for (int ni = 0; ni < NT; ni++) {
            const int col = cb + ni * 16;
#pragma unroll
            for (int r = 0; r < 4; r++) {
                const int row = rb + mi * 16 + r;
                const float v = acc[mi][ni][r];
                if constexpr (MODE == 0) {
                    ((u16*)C)[(size_t)row * N + col] = f2bf(v);
                } else if constexpr (MODE == 5) {
                    ((float*)C)[((size_t)blockIdx.z * M + row) * N + col] = v;
                }
            }
        }
    }
}

// ---------------- reduce split-K partials -> x_dbl fp32 + dtin bf16 ---------
__global__ void reduce_xdbl(const float* __restrict__ part,
                            float* __restrict__ x_dbl, u16* __restrict__ dtin) {
    const int idx = blockIdx.x * 256 + threadIdx.x;   // 2048*160
    const int row = idx / 160, col = idx - row * 160;
    float s = 0.f;
#pragma unroll
    for (int z = 0; z < 8; z++) s += part[(size_t)z * (2048 * 160) + idx];
    x_dbl[idx] = s;
    if (col < 128) dtin[row * 128 + col] = f2bf(s);
}

// ---------------- dedicated dt GEMM: dt = softplus(dtin @ W_dtT^T + b) ------
// M=2048, N=4096, K=128 (whole K staged once). 64x64 tile, 2048 blocks.
// Epilogue: acc -> LDS fp32 [64][68] -> float4 coalesced global stores.
__global__ __launch_bounds__(256) void dt_gemm(
    const u16* __restrict__ A,      // dtin  [2048 x 128] bf16
    const u16* __restrict__ Bt,     // W_dtT [4096 x 128] bf16
    float* __restrict__ C,          // dtv   [2048 x 4096] fp32
    const u16* __restrict__ bias)   // b_dt  [4096] bf16
{
    __shared__ ulong4 smem_raw[2048];            // 32 KB
    u16* As = (u16*)smem_raw;                    // [64][128] swizzled bf16
    u16* Bs = As + 64 * 128;                     // [64][128] swizzled bf16
    float* Cs = (float*)smem_raw;                // [64][68] fp32 (aliases As/Bs)

    const int tid  = threadIdx.x;
    const int lane = tid & 63;
    const int wave = tid >> 6;
    const int n0 = blockIdx.x * 64;
    const int m0 = blockIdx.y * 64;

    // stage A and B tiles: 64 rows x 16 chunks (16 B) each, 4 iters x 256 thr.
#pragma unroll
    for (int it = 0; it < 4; it++) {
        const int c = it * 256 + tid;
        const int row = c >> 4, cc = (c & 15) ^ (row & 7);
        const u16* gp = &A[(size_t)(m0 + row) * 128 + cc * 8];
        __builtin_amdgcn_global_load_lds(
            (const __attribute__((address_space(1))) void*)gp,
            (__attribute__((address_space(3))) void*)&As[c * 8], 16, 0, 0);
    }
#pragma unroll
    for (int it = 0; it < 4; it++) {
        const int c = it * 256 + tid;
        const int row = c >> 4, cc = (c & 15) ^ (row & 7);
        const u16* gp = &Bt[(size_t)(n0 + row) * 128 + cc * 8];
        __builtin_amdgcn_global_load_lds(
            (const __attribute__((address_space(1))) void*)gp,
            (__attribute__((address_space(3))) void*)&Bs[c * 8], 16, 0, 0);
    }
    __syncthreads();

    // wave w owns rows m0 + w*16 .. +15, all 64 cols of the tile.
    const int q  = lane >> 4;                 // k-quad this lane consumes
    const int ar = wave * 16 + (lane & 15);   // A row within tile
    f32x4 acc[4];
#pragma unroll
    for (int ni = 0; ni < 4; ni++) acc[ni] = (f32x4){0.f, 0.f, 0.f, 0.f};

#pragma unroll
    for (int kk = 0; kk < 4; kk++) {          // 4 k-slabs of 32
        const int cA = kk * 4 + q;            // 16B chunk index within row
        const bf16x8 af = *reinterpret_cast<const bf16x8*>(
            &As[(ar * 16 + (cA ^ (ar & 7))) * 8]);
#pragma unroll
        for (int ni = 0; ni < 4; ni++) {
            const int br = ni * 16 + (lane & 15);
            const bf16x8 bfr = *reinterpret_cast<const bf16x8*>(
                &Bs[(br * 16 + (cA ^ (br & 7))) * 8]);
            acc[ni] = __builtin_amdgcn_mfma_f32_16x16x32_bf16(af, bfr, acc[ni], 0, 0, 0);
        }
    }
    __syncthreads();   // all As/Bs reads done before Cs overwrites them

    // fragment -> LDS fp32 tile (stride 68 breaks the 256B bank aliasing)
#pragma unroll
    for (int ni = 0; ni < 4; ni++) {
        const int col = ni * 16 + (lane & 15);
#pragma unroll
        for (int r = 0; r < 4; r++) {
            const int rowl = wave * 16 + q * 4 + r;
            Cs[rowl * 68 + col] = acc[ni][r];
        }
    }
    __syncthreads();

    // LDS -> global: 4 passes x float4 per thread; bias + softplus fused.
#pragma unroll
    for (int p = 0; p < 4; p++) {
        const int rowl = p * 16 + (tid >> 4);
        const int c0 = (tid & 15) * 4;
        float4 v = *reinterpret_cast<const float4*>(&Cs[rowl * 68 + c0]);
        float* vp = reinterpret_cast<float*>(&v);
#pragma unroll
        for (int j = 0; j < 4; j++) {
            const float x = vp[j] + bf2f(bias[n0 + c0 + j]);
            // softplus(x) = max(x,0) + log1p(exp(-|x|)); fast hw exp/log
            vp[j] = fmaxf(x, 0.f) + __logf(1.f + __expf(-fabsf(x)));
        }
        *reinterpret_cast<float4*>(&C[(size_t)(m0 + rowl) * 4096 + n0 + c0]) = v;
    }
}

// ---------------- depthwise conv3 + bias + silu (8 ch/thread) ---------------
__global__ void conv_silu(const u16* __restrict__ xz, const u16* __restrict__ conv_w,
                          const u16* __restrict__ conv_b, u16* __restrict__ xc) {
    const int idx = blockIdx.x * 256 + threadIdx.x;    // 2048*512 threads
    const int row = idx >> 9, c0 = (idx & 511) * 8;
    const int l = row & 1023;

    u16 wcat[24];
    *(u16x8*)&wcat[0]  = *(const u16x8*)&conv_w[c0 * 3];
    *(u16x8*)&wcat[8]  = *(const u16x8*)&conv_w[c0 * 3 + 8];
    *(u16x8*)&wcat[16] = *(const u16x8*)&conv_w[c0 * 3 + 16];
    const u16x8 bv = *(const u16x8*)&conv_b[c0];
    const u16x8 x0 = *(const u16x8*)&xz[(size_t)row * 8192 + c0];
    u16x8 xm = {}, xp = {};
    if (l > 0)    xm = *(const u16x8*)&xz[(size_t)(row - 1) * 8192 + c0];
    if (l < 1023) xp = *(const u16x8*)&xz[(size_t)(row + 1) * 8192 + c0];

    u16x8 out;
#pragma unroll
    for (int i = 0; i < 8; i++) {
        float v = bf2f(wcat[3 * i]) * bf2f(xm[i])
                + bf2f(wcat[3 * i + 1]) * bf2f(x0[i])
                + bf2f(wcat[3 * i + 2]) * bf2f(xp[i])
                + bf2f(bv[i]);
        v = v / (1.f + __expf(-v));
        out[i] = f2bf(v);
    }
    *(u16x8*)&xc[(size_t)row * 4096 + c0] = out;
}

// ---------------- S1: per-chunk local scan (h_in = 0), lane = channel -------
// grid (NCHUNK, 16, 2), 256 threads: lane owns all 16 states of one channel.
__global__ __launch_bounds__(256) void scan_p1(
    const float* __restrict__ dt, const u16* __restrict__ xc,
    const float* __restrict__ x_dbl, const u16* __restrict__ A_log,
    float* __restrict__ Parr, u16* __restrict__ xzbase)
{
    __shared__ float Bsm[CLEN][16];
    const int tid = threadIdx.x;
    const int nc = blockIdx.x, cg = blockIdx.y, b = blockIdx.z;
    const int ch = cg * 256 + tid;
    const size_t row0 = (size_t)b * 1024 + nc * CLEN;

    {   // stage B[t][s]: 64 rows x 16 floats; 256 threads x 1 float4
        const int t = tid >> 2, q = tid & 3;
        const float4 v = *(const float4*)&x_dbl[(row0 + t) * 160 + 128 + q * 4];
        *(float4*)&Bsm[t][q * 4] = v;
    }
    __syncthreads();

    float A_s[16], h[16];
#pragma unroll
    for (int s = 0; s < 16; s++) {
        A_s[s] = -__expf(bf2f(A_log[ch * 16 + s]));
        h[s] = 0.f;
    }
    float Sdt = 0.f;

    float dt_v = dt[row0 * 4096 + ch];
    float u_v  = bf2f(xc[row0 * 4096 + ch]);
    for (int t = 0; t < CLEN; t++) {
        const int tn = (t + 1 < CLEN) ? t + 1 : t;
        const float dt_n = dt[(row0 + tn) * 4096 + ch];
        const float u_n  = bf2f(xc[(row0 + tn) * 4096 + ch]);
        const float dtu = dt_v * u_v;
        Sdt += dt_v;
        const f32x4* Brow = (const f32x4*)&Bsm[t][0];
        const f32x4 B0 = Brow[0], B1 = Brow[1], B2 = Brow[2], B3 = Brow[3];
#pragma unroll
        for (int s = 0; s < 16; s++) {
            const float Bs_ = (s < 4 ? B0[s & 3] : s < 8 ? B1[s & 3] : s < 12 ? B2[s & 3] : B3[s & 3]);
            const float dA = __expf(dt_v * A_s[s]);
            h[s] = dA * h[s] + dtu * Bs_;
        }
        dt_v = dt_n; u_v = u_n;
    }
    const int i0 = (((b * NCHUNK + nc) * 4096) + ch) * 16;
    float* pp = &Parr[i0];
    float* hp = hloc_ptr(xzbase, i0);
#pragma unroll
    for (int s4 = 0; s4 < 4; s4++) {
        float4 pq, hq;
        pq.x = __expf(A_s[4 * s4 + 0] * Sdt);
        pq.y = __expf(A_s[4 * s4 + 1] * Sdt);
        pq.z = __expf(A_s[4 * s4 + 2] * Sdt);
        pq.w = __expf(A_s[4 * s4 + 3] * Sdt);
        hq.x = h[4 * s4 + 0]; hq.y = h[4 * s4 + 1];
        hq.z = h[4 * s4 + 2]; hq.w = h[4 * s4 + 3];
        *(float4*)&pp[4 * s4] = pq;
        *(float4*)&hp[4 * s4] = hq;
    }
}

// ---------------- S2: combine chunk summaries -> h_in -----------------------
__global__ __launch_bounds__(256) void scan_p2(
    const float* __restrict__ Parr, u16* __restrict__ xzbase)
{
    const int tid = threadIdx.x;
    const int lane = tid & 63, wave = tid >> 6;
    const int blk = blockIdx.x;
    const int b = blk >> 8, cg = blk & 255;
    const int c_local = lane & 3, s = lane >> 2;
    const int ch = cg * 16 + wave * 4 + c_local;

    float Pv[NCHUNK], hl[NCHUNK];
#pragma unroll
    for (int c = 0; c < NCHUNK; c++) {
        const int i = (((b * NCHUNK + c) * 4096) + ch) * 16 + s;
        Pv[c] = Parr[i];
        hl[c] = *hloc_ptr(xzbase, i);
    }
    float hin = 0.f;
#pragma unroll
    for (int c = 0; c < NCHUNK; c++) {
        const int i = (((b * NCHUNK + c) * 4096) + ch) * 16 + s;
        *hin_ptr(xzbase, i) = hin;
        hin = Pv[c] * hin + hl[c];
    }
}

// ---------------- S3: rescan with h_in; fused gate; lane = channel ----------
__global__ __launch_bounds__(256) void scan_p3(
    const float* __restrict__ dt, const u16* __restrict__ xc,
    const float* __restrict__ x_dbl, const u16* __restrict__ xz,
    const u16* __restrict__ A_log, const u16* __restrict__ Dp,
    u16* __restrict__ yg, u16* __restrict__ xzbase)
{
    __shared__ float BCs[CLEN][32];   // [t][0..15]=B, [t][16..31]=C
    const int tid = threadIdx.x;
    const int nc = blockIdx.x, cg = blockIdx.y, b = blockIdx.z;
    const int ch = cg * 256 + tid;
    const size_t row0 = (size_t)b * 1024 + nc * CLEN;

#pragma unroll
    for (int it = 0; it < 2; it++) {   // 64 rows x 32 floats; 512 float4
        const int c = it * 256 + tid;
        const int t = c >> 3, q = c & 7;
        const float4 v = *(const float4*)&x_dbl[(row0 + t) * 160 + 128 + q * 4];
        *(float4*)&BCs[t][q * 4] = v;
    }
    __syncthreads();

    float A_s[16], h[16];
    const int i0 = (((b * NCHUNK + nc) * 4096) + ch) * 16;
    {
        const float* hp = hin_ptr(xzbase, i0);
#pragma unroll
        for (int s4 = 0; s4 < 4; s4++) {
            const float4 hq = *(const float4*)&hp[4 * s4];
            h[4 * s4 + 0] = hq.x; h[4 * s4 + 1] = hq.y;
            h[4 * s4 + 2] = hq.z; h[4 * s4 + 3] = hq.w;
        }
    }
#pragma unroll
    for (int s = 0; s < 16; s++)
        A_s[s] = -__expf(bf2f(A_log[ch * 16 + s]));
    const float D_ch = bf2f(Dp[ch]);

    float dt_v = dt[row0 * 4096 + ch];
    float u_v  = bf2f(xc[row0 * 4096 + ch]);
    float z_v  = bf2f(xz[row0 * 8192 + 4096 + ch]);
    for (int t = 0; t < CLEN; t++) {
        const int tn = (t + 1 < CLEN) ? t + 1 : t;
        const size_t rn = row0 + tn;
        const float dt_n = dt[rn * 4096 + ch];
        const float u_n  = bf2f(xc[rn * 4096 + ch]);
        const float z_n  = bf2f(xz[rn * 8192 + 4096 + ch]);
        const float dtu = dt_v * u_v;

        const f32x4* Row = (const f32x4*)&BCs[t][0];
        const f32x4 B0 = Row[0], B1 = Row[1], B2 = Row[2], B3 = Row[3];
        const f32x4 C0 = Row[4], C1 = Row[5], C2 = Row[6], C3 = Row[7];

        float y0 = 0.f, y1 = 0.f, y2 = 0.f, y3 = 0.f;
#pragma unroll
        for (int s = 0; s < 16; s++) {
            const float Bs_ = (s < 4 ? B0[s & 3] : s < 8 ? B1[s & 3] : s < 12 ? B2[s & 3] : B3[s & 3]);
            const float Cs_ = (s < 4 ? C0[s & 3] : s < 8 ? C1[s & 3] : s < 12 ? C2[s & 3] : C3[s & 3]);
            const float dA = __expf(dt_v * A_s[s]);
            h[s] = dA * h[s] + dtu * Bs_;
            const float hc = h[s] * Cs_;
            if ((s & 3) == 0) y0 += hc; else if ((s & 3) == 1) y1 += hc;
            else if ((s & 3) == 2) y2 += hc; else y3 += hc;
        }
        const float y = (y0 + y1) + (y2 + y3);
        const float silu_z = z_v / (1.f + __expf(-z_v));
        yg[(row0 + t) * 4096 + ch] = f2bf((y + u_v * D_ch) * silu_z);
        dt_v = dt_n; u_v = u_n; z_v = z_n;
    }
}

extern "C" void kernel_launch(void* const* d_in, const int* in_sizes, int n_in,
                              void* d_out, int out_size, void* d_ws, size_t ws_size,
                              hipStream_t stream)
{
    const void* x_raw      = d_in[0];   // (2,1024,2048)
    const void* W_in_raw   = d_in[1];   // (2048,8192)
    const void* conv_w_raw = d_in[2];   // (4096,1,3)
    const void* conv_b_raw = d_in[3];   // (4096)
    const void* W_x_raw    = d_in[4];   // (4096,160)
    const void* W_dt_raw   = d_in[5];   // (128,4096)
    const void* b_dt_raw   = d_in[6];   // (4096)
    const void* A_log_raw  = d_in[7];   // (4096,16)
    const void* D_raw      = d_in[8];   // (4096)
    const void* W_out_raw  = d_in[9];   // (4096,2048)

    char* ws = (char*)d_ws;
    size_t off = 0;
    auto alloc = [&](size_t bytes) { char* p = ws + off; off += (bytes + 255) & ~(size_t)255; return p; };
    int*   flag   = (int*)  alloc(4);
    u16*   W_inT  = (u16*)  alloc(8192ULL * 2048 * 2);   // 32 MB (aliased by dt fp32 after K1)
    u16*   W_outT = (u16*)  alloc(2048ULL * 4096 * 2);   // 16 MB
    u16*   W_dtT  = (u16*)  alloc(4096ULL * 128 * 2);    // 1 MB
    u16*   W_xT   = (u16*)  alloc(160ULL * 4096 * 2);    // 1.25 MB
    u16*   xz     = (u16*)  alloc(2048ULL * 8192 * 2);   // 32 MB (xp half reused as h_loc/h_in)
    u16*   xc     = (u16*)  alloc(2048ULL * 4096 * 2);   // 16 MB
    float* x_dbl  = (float*)alloc(2048ULL * 160 * 4);    // 1.25 MB
    u16*   dtin   = (u16*)  alloc(2048ULL * 128 * 2);    // 0.5 MB
    u16*   yg     = (u16*)  alloc(2048ULL * 4096 * 2);   // 16 MB
    u16*   xcan   = (u16*)  alloc(2048ULL * 2048 * 2);   // 8 MB (reused as Parr fp32)
    float* xdblp  = (float*)alloc(8ULL * 2048 * 160 * 4);// 10.5 MB split-K partials
    u16*   cw_c   = (u16*)  alloc(12288 * 2);
    u16*   cb_c   = (u16*)  alloc(4096 * 2);
    u16*   bdt_c  = (u16*)  alloc(4096 * 2);
    u16*   Alog_c = (u16*)  alloc(65536 * 2);
    u16*   D_c    = (u16*)  alloc(4096 * 2);
    float* dtv    = (float*)W_inT;   // alias: W_inT dead after K1 (32 MB exact)
    float* Parr   = (float*)xcan;    // alias: xcan dead after K1 (8 MB exact)

    // D) dtype flag, fused canonicalize
    detect_dtype<<<1, 256, 0, stream>>>((const u16*)x_raw, flag);
    cvt_fused<<<2048 + 6 + 2 + 2 + 32 + 2, 256, 0, stream>>>(
        x_raw, xcan, conv_w_raw, cw_c, conv_b_raw, cb_c, b_dt_raw, bdt_c,
        A_log_raw, Alog_c, D_raw, D_c, flag);

    // T) fused transposes (64x32 tiles, vec reads, u32 writes)
    transpose_fused<<<8192 + 4096 + 256 + 320, dim3(32, 8), 0, stream>>>(
        W_in_raw, W_inT, W_out_raw, W_outT, W_dt_raw, W_dtT, W_x_raw, W_xT, flag);

    // K1: xz = x @ W_in   (M=2048, N=8192, K=2048), 256^2 ring-4 2-phase
    (void)hipFuncSetAttribute(
        reinterpret_cast<const void*>(&gemm_ring<256, 256, 2, 4, 0>),
        hipFuncAttributeMaxDynamicSharedMemorySize, 131072);
    gemm_ring<256, 256, 2, 4, 0><<<dim3(8192 / 256, 2048 / 256), 512, 131072, stream>>>(
        xcan, W_inT, xz, nullptr, 2048, 8192, 2048);

    // K2: conv + bias + silu (8 ch/thread)
    conv_silu<<<(2048 * 512) / 256, 256, 0, stream>>>(xz, cw_c, cb_c, xc);

    // K3: x_dbl partials = xc @ W_x   (split-K=8, plain fp32 stores)
    gemm_bt<64, 160, 32, 4, 1, 1, 10, 5>
        <<<dim3(1, 2048 / 64, 8), 256, 0, stream>>>(xc, W_xT, xdblp, nullptr, nullptr, 2048, 160, 4096);

    // R) reduce partials -> x_dbl fp32 + dtin bf16 (replaces cvt_dtin)
    reduce_xdbl<<<(2048 * 160) / 256, 256, 0, stream>>>(xdblp, x_dbl, dtin);

    // K4: dt = softplus(dtin @ W_dt + b_dt)   (fp32 out, dedicated kernel)
    dt_gemm<<<dim3(4096 / 64, 2048 / 64), 256, 0, stream>>>(dtin, W_dtT, dtv, bdt_c);

    // S1/S2/S3: chunked selective scan (lane=channel) with fused gating
    scan_p1<<<dim3(NCHUNK, 16, 2), 256, 0, stream>>>(dtv, xc, x_dbl, Alog_c, Parr, xz);
    scan_p2<<<512, 256, 0, stream>>>(Parr, xz);
    scan_p3<<<dim3(NCHUNK, 16, 2), 256, 0, stream>>>(dtv, xc, x_dbl, xz, Alog_c, D_c, yg, xz);

    // K6: out = yg @ W_out   (M=2048, N=2048, K=4096), 128^2 ring-4 2-phase
    (void)hipFuncSetAttribute(
        reinterpret_cast<const void*>(&gemm_ring<128, 128, 2, 2, 1>),
        hipFuncAttributeMaxDynamicSharedMemorySize, 65536);
    gemm_ring<128, 128, 2, 2, 1><<<dim3(2048 / 128, 2048 / 128), 256, 65536, stream>>>(
        yg, W_outT, d_out, flag, 2048, 2048, 4096);
}

// Round 8
// 407.256 us; speedup vs baseline: 1.1022x; 1.0038x over previous
//
#include <hip/hip_runtime.h>
#include <hip/hip_bf16.h>

// Selective SSM (Mamba-style): B=2, L=1024, H=2048, E=2 -> d=4096, S=16, R=128.
// Round 15: (a) gemm_ring: per-phase af PREFETCH (phase g issues phase g+1's
// ds_reads before its MFMA cluster, m201-style) — hides LDS latency under
// MFMA; all reads still target tile t's buffer (ring WAR unchanged).
// (b) K6 split-K=2 via ring MODE 2 (fp32 partials at z offset): 256->512
// blocks (1->2 blocks/CU, 2 waves/SIMD), half K-loop; reduce_out sums
// partials with flag-aware store. Partials alias dead dtv/W_inT (33.5 MB).

using u16 = unsigned short;
typedef __bf16 bf16x8 __attribute__((ext_vector_type(8)));
typedef float f32x4 __attribute__((ext_vector_type(4)));
typedef u16 u16x8 __attribute__((ext_vector_type(8)));
typedef u16 u16x4 __attribute__((ext_vector_type(4)));

#define NCHUNK 16
#define CLEN   64
// chunk swizzle: quad j of row r lives at chunk r*4 + (j ^ ((r>>1)&3))
#define SWZ(row, q) ((q) ^ (((row) >> 1) & 3))

__device__ __forceinline__ float bf2f(u16 u) {
    union { unsigned int i; float f; } v; v.i = ((unsigned int)u) << 16; return v.f;
}
__device__ __forceinline__ u16 f2bf(float f) {
    union { float f; unsigned int i; } v; v.f = f;
    unsigned int x = v.i;
    return (u16)((x + 0x7FFFu + ((x >> 16) & 1u)) >> 16);   // RNE
}

// fp32 scratch carved out of the dead xp-column half of xz (rows x 8192 u16;
// cols 0..4095 dead after conv). h_loc: rows 0..1023, h_in: rows 1024..2047.
__device__ __forceinline__ float* hloc_ptr(u16* xzbase, int i) {
    return reinterpret_cast<float*>(xzbase + (size_t)(i >> 11) * 8192) + (i & 2047);
}
__device__ __forceinline__ float* hin_ptr(u16* xzbase, int i) {
    return reinterpret_cast<float*>(xzbase + (size_t)((i >> 11) + 1024) * 8192) + (i & 2047);
}

// ---------------- dtype detection -------------------------------------------
__global__ void detect_dtype(const u16* __restrict__ xraw, int* __restrict__ flag) {
    __shared__ int cnt[256];
    const int tid = threadIdx.x;
    int plausible = 0;
    for (int i = tid; i < 4096; i += 256) {
        const u16 v = xraw[2 * i];
        const int e = (v >> 7) & 0xFF;
        plausible += (e >= 100 && e <= 145) ? 1 : 0;
    }
    cnt[tid] = plausible;
    __syncthreads();
    for (int s = 128; s > 0; s >>= 1) {
        if (tid < s) cnt[tid] += cnt[tid + s];
        __syncthreads();
    }
    if (tid == 0) *flag = (cnt[0] > 2458) ? 1 : 0;
}

// ---------------- fused canonicalize (6 tensors), 8 elems/thread ------------
__device__ __forceinline__ void cvt_seg8(const void* src, u16* dst, int i8,
                                         bool isbf) {
    if (isbf) {
        *(u16x8*)&dst[i8 * 8] = *((const u16x8*)src + i8);
    } else {
        const float* f = (const float*)src + i8 * 8;
        u16x8 o;
#pragma unroll
        for (int j = 0; j < 8; j++) o[j] = f2bf(f[j]);
        *(u16x8*)&dst[i8 * 8] = o;
    }
}
__global__ void cvt_fused(const void* __restrict__ x_raw, u16* __restrict__ xcan,
                          const void* __restrict__ cw_raw, u16* __restrict__ cw_c,
                          const void* __restrict__ cb_raw, u16* __restrict__ cb_c,
                          const void* __restrict__ bdt_raw, u16* __restrict__ bdt_c,
                          const void* __restrict__ Alog_raw, u16* __restrict__ Alog_c,
                          const void* __restrict__ D_raw, u16* __restrict__ D_c,
                          const int* __restrict__ flag) {
    const bool isbf = (*flag != 0);
    int blk = blockIdx.x;
    const int tid = threadIdx.x;
    if (blk < 2048) { cvt_seg8(x_raw, xcan, blk * 256 + tid, isbf); return; }   // 4.19M
    blk -= 2048;
    if (blk < 6)  { cvt_seg8(cw_raw, cw_c, blk * 256 + tid, isbf); return; }    // 12288
    blk -= 6;
    if (blk < 2)  { cvt_seg8(cb_raw, cb_c, blk * 256 + tid, isbf); return; }    // 4096
    blk -= 2;
    if (blk < 2)  { cvt_seg8(bdt_raw, bdt_c, blk * 256 + tid, isbf); return; }  // 4096
    blk -= 2;
    if (blk < 32) { cvt_seg8(Alog_raw, Alog_c, blk * 256 + tid, isbf); return; }// 65536
    blk -= 32;
    cvt_seg8(D_raw, D_c, blk * 256 + tid, isbf);                                 // 4096
}

// ---------------- fused flag-aware transposes (4 tensors) -------------------
// 64(rows) x 32(cols) input tile; u16x2/float2 reads; u32 transposed writes.
__device__ __forceinline__ void tr_tile(const void* in, u16* out, int R, int C,
                                        int bx, int by, int tx, int ty, bool isbf,
                                        u16 (*tile)[34]) {
    const int c0 = bx * 32, r0 = by * 64;
    const int cp = tx & 15, rh = tx >> 4;      // colpair 0..15, row-half 0/1
#pragma unroll
    for (int i = 0; i < 4; i++) {
        const int row = ty + rh * 8 + i * 16;
        const size_t idx = (size_t)(r0 + row) * C + c0 + cp * 2;
        if (isbf) {
            union { unsigned int u; u16 h[2]; } p;
            p.u = *reinterpret_cast<const unsigned int*>(&((const u16*)in)[idx]);
            tile[row][cp * 2] = p.h[0];
            tile[row][cp * 2 + 1] = p.h[1];
        } else {
            const float2 f = *reinterpret_cast<const float2*>(&((const float*)in)[idx]);
            tile[row][cp * 2] = f2bf(f.x);
            tile[row][cp * 2 + 1] = f2bf(f.y);
        }
    }
    __syncthreads();
#pragma unroll
    for (int i = 0; i < 4; i++) {
        const int w = ty + i * 8;                       // output row-local 0..31
        union { u16 h[2]; unsigned int u; } p;
        p.h[0] = tile[2 * tx][w];
        p.h[1] = tile[2 * tx + 1][w];
        *reinterpret_cast<unsigned int*>(&out[(size_t)(c0 + w) * R + r0 + 2 * tx]) = p.u;
    }
}
__global__ void transpose_fused(const void* __restrict__ Wi, u16* __restrict__ WiT,
                                const void* __restrict__ Wo, u16* __restrict__ WoT,
                                const void* __restrict__ Wd, u16* __restrict__ WdT,
                                const void* __restrict__ Wx, u16* __restrict__ WxT,
                                const int* __restrict__ flag) {
    __shared__ u16 tile[64][34];
    const bool isbf = (*flag != 0);
    const int tx = threadIdx.x, ty = threadIdx.y;   // (32,8)
    int blk = blockIdx.x;
    if (blk < 8192) { tr_tile(Wi, WiT, 2048, 8192, blk % 256, blk / 256, tx, ty, isbf, tile); return; }
    blk -= 8192;
    if (blk < 4096) { tr_tile(Wo, WoT, 4096, 2048, blk % 64, blk / 64, tx, ty, isbf, tile); return; }
    blk -= 4096;
    if (blk < 256)  { tr_tile(Wd, WdT, 128, 4096, blk % 128, blk / 128, tx, ty, isbf, tile); return; }
    blk -= 256;
    tr_tile(Wx, WxT, 4096, 160, blk % 5, blk / 5, tx, ty, isbf, tile);   // 320 blocks
}

// ---------------- ring-4 deep-pipelined bf16 GEMM (2-phase, af-prefetch) ----
// C[M,N] = A[M,K] * Bt[N,K]^T. 64*WM*WN threads; per-wave output
// (BM/WM) x (BN/WN). BK=32; LDS ring of 4 tile-buffers; staging runs 3 tiles
// ahead; per-tile s_waitcnt vmcnt(12) retires only the tile about to be
// consumed (4 loads/thread/stage). Raw s_barrier (no __syncthreads) so the
// compiler cannot force a vmcnt(0) drain. Compute split into NPH=2 phases of
// MT/2 x NT MFMA; phase g issues phase g+1's af ds_reads BEFORE its MFMA
// cluster so the LDS latency hides under the MFMAs (m201 pattern). All reads
// target tile t's buffer (valid until exit barrier) -> ring WAR unchanged.
// Split-K: grid.z chunks K; Kchunk = K/gridDim.z (MODE 2 stores fp32
// partials at z offset). MODE 0: bf16 store. MODE 1: flag-aware store.
template <int BM, int BN, int THR>
__device__ __forceinline__ void stage_ring(const u16* __restrict__ Ab,
                                           const u16* __restrict__ Bb,
                                           int K, int k0, u16* dst, int tid)
{
    constexpr int CHA = BM * 4, CHB = BN * 4;
    static_assert(CHA % THR == 0 && CHB % THR == 0, "chunk/thread mismatch");
#pragma unroll
    for (int it = 0; it < CHA / THR; it++) {
        const int c = it * THR + tid;
        const int row = c >> 2, kc = SWZ(row, c & 3);
        __builtin_amdgcn_global_load_lds(
            (const __attribute__((address_space(1))) void*)(Ab + (size_t)row * K + k0 + kc * 8),
            (__attribute__((address_space(3))) void*)(dst + c * 8), 16, 0, 0);
    }
#pragma unroll
    for (int it = 0; it < CHB / THR; it++) {
        const int c = it * THR + tid;
        const int row = c >> 2, kc = SWZ(row, c & 3);
        __builtin_amdgcn_global_load_lds(
            (const __attribute__((address_space(1))) void*)(Bb + (size_t)row * K + k0 + kc * 8),
            (__attribute__((address_space(3))) void*)(dst + BM * 32 + c * 8), 16, 0, 0);
    }
}

template <int BM, int BN, int WM, int WN, int MODE>
__global__ __launch_bounds__(64 * WM * WN, 2) void gemm_ring(
    const u16* __restrict__ A, const u16* __restrict__ Bt, void* __restrict__ C,
    const int* __restrict__ oflagp, int M, int N, int K)
{
    constexpr int THR = 64 * WM * WN;
    constexpr int MT  = BM / (WM * 16);
    constexpr int NT  = BN / (WN * 16);
    constexpr int NPH = 2;                       // compute phases per K-tile
    constexpr int GM  = MT / NPH;                // mi-rows per phase
    constexpr int STG = (BM + BN) * 32;          // u16 per ring stage
    static_assert((BM * 4 + BN * 4) / THR == 4, "vmcnt ladder assumes 4 loads/thread/stage");
    static_assert(MT % NPH == 0, "MT must split into NPH phases");
    extern __shared__ u16 smem[];                // 4 * STG u16

    const int tid  = threadIdx.x;
    const int lane = tid & 63;
    const int wave = tid >> 6;
    const int wm = wave / WN, wn = wave % WN;
    const int q  = lane >> 4;                    // k-quad this lane consumes
    const int n0 = blockIdx.x * BN;
    const int m0 = blockIdx.y * BM;
    const int Kchunk = K / gridDim.z;
    const int kbeg = blockIdx.z * Kchunk;
    const int NTILE = Kchunk >> 5;               // BK=32 tiles

    const u16* Ab = A  + (size_t)m0 * K + kbeg;
    const u16* Bb = Bt + (size_t)n0 * K + kbeg;

    // prologue: tiles 0..2 in flight (12 loads/thread)
    stage_ring<BM, BN, THR>(Ab, Bb, K, 0,  smem + 0 * STG, tid);
    stage_ring<BM, BN, THR>(Ab, Bb, K, 32, smem + 1 * STG, tid);
    stage_ring<BM, BN, THR>(Ab, Bb, K, 64, smem + 2 * STG, tid);

    f32x4 acc[MT][NT];
#pragma unroll
    for (int mi = 0; mi < MT; mi++)
#pragma unroll
        for (int ni = 0; ni < NT; ni++)
            acc[mi][ni] = (f32x4){0.f, 0.f, 0.f, 0.f};

    const int arow = wm * (MT * 16) + (lane & 15);
    const int brow = wn * (NT * 16) + (lane & 15);

    for (int t = 0; t < NTILE; t++) {
        const int tp = t + 3;
        if (tp < NTILE) {
            stage_ring<BM, BN, THR>(Ab, Bb, K, tp * 32, smem + (tp & 3) * STG, tid);
            asm volatile("s_waitcnt vmcnt(12)" ::: "memory");   // tile t landed
        } else if (tp == NTILE) {
            asm volatile("s_waitcnt vmcnt(8)" ::: "memory");
        } else if (tp == NTILE + 1) {
            asm volatile("s_waitcnt vmcnt(4)" ::: "memory");
        } else {
            asm volatile("s_waitcnt vmcnt(0)" ::: "memory");
        }
        __builtin_amdgcn_s_barrier();            // tile t visible to all

        const u16* As = smem + (t & 3) * STG;
        const u16* Bs = As + BM * 32;
        bf16x8 bfr[NT], af[MT];
#pragma unroll
        for (int ni = 0; ni < NT; ni++) {
            const int r = brow + ni * 16;
            bfr[ni] = *reinterpret_cast<const bf16x8*>(&Bs[r * 32 + SWZ(r, q) * 8]);
        }
#pragma unroll
        for (int i = 0; i < GM; i++) {           // phase-0 fragments
            const int r = arow + i * 16;
            af[i] = *reinterpret_cast<const bf16x8*>(&As[r * 32 + SWZ(r, q) * 8]);
        }
#pragma unroll
        for (int g = 0; g < NPH; g++) {
            if (g + 1 < NPH) {                   // prefetch next phase's af
#pragma unroll
                for (int i = 0; i < GM; i++) {
                    const int r = arow + ((g + 1) * GM + i) * 16;
                    af[(g + 1) * GM + i] =
                        *reinterpret_cast<const bf16x8*>(&As[r * 32 + SWZ(r, q) * 8]);
                }
            }
            __builtin_amdgcn_s_setprio(1);
#pragma unroll
            for (int i = 0; i < GM; i++)
#pragma unroll
                for (int ni = 0; ni < NT; ni++)
                    acc[g * GM + i][ni] = __builtin_amdgcn_mfma_f32_16x16x32_bf16(
                        af[g * GM + i], bfr[ni], acc[g * GM + i][ni], 0, 0, 0);
            __builtin_amdgcn_s_setprio(0);
            __builtin_amdgcn_sched_barrier(0);   // pin phase reads before barrier
            __builtin_amdgcn_s_barrier();        // phase boundary (last = exit)
        }
    }

    int oflag = 1;
    if constexpr (MODE == 1) oflag = *oflagp;    // after loop: vmcnt already 0

    const int rb = m0 + wm * (MT * 16) + (q << 2);
    const int cb = n0 + wn * (NT * 16) + (lane & 15);
#pragma unroll
    for (int mi = 0; mi < MT; mi++) {
#pragma unroll
        for (int ni = 0; ni < NT; ni++) {
            const int col = cb + ni * 16;
#pragma unroll
            for (int r = 0; r < 4; r++) {
                const int row = rb + mi * 16 + r;
                const float v = acc[mi][ni][r];
                if constexpr (MODE == 0) {
                    ((u16*)C)[(size_t)row * N + col] = f2bf(v);
                } else if constexpr (MODE == 2) {
                    ((float*)C)[((size_t)blockIdx.z * M + row) * N + col] = v;
                } else {
                    if (oflag) ((u16*)C)[(size_t)row * N + col] = f2bf(v);
                    else       ((float*)C)[(size_t)row * N + col] = v;
                }
            }
        }
    }
}

// ---------------- reduce K6 split-K partials -> d_out (flag-aware) ----------
__global__ void reduce_out(const float* __restrict__ part, void* __restrict__ out,
                           const int* __restrict__ flag) {
    const int idx = blockIdx.x * 256 + threadIdx.x;     // 1,048,576 threads
    const int i4 = idx * 4;
    const float4 a = *(const float4*)&part[i4];
    const float4 b = *(const float4*)&part[(size_t)4194304 + i4];
    if (*flag) {
        u16x4 o;
        o[0] = f2bf(a.x + b.x); o[1] = f2bf(a.y + b.y);
        o[2] = f2bf(a.z + b.z); o[3] = f2bf(a.w + b.w);
        *(u16x4*)&((u16*)out)[i4] = o;
    } else {
        float4 s = {a.x + b.x, a.y + b.y, a.z + b.z, a.w + b.w};
        *(float4*)&((float*)out)[i4] = s;
    }
}

// ---------------- generic bf16 MFMA GEMM:  C[M,N] = A[M,K] * Bt[N,K]^T -------
// (kept for K3's split-K path; MODE 5 = per-z fp32 partial stores, no atomics)
template <int BM, int BN, int BK, int WR, int WC, int MT, int NT, int MODE>
__global__ __launch_bounds__(256) void gemm_bt(
    const u16* __restrict__ A, const u16* __restrict__ Bt,
    void* __restrict__ C, const u16* __restrict__ bias,
    const int* __restrict__ oflagp,
    int M, int N, int K)
{
    static_assert(BK == 32, "BK=32 (one 16x16x32 MFMA k-slab)");
    __shared__ u16 As[BM * BK];
    __shared__ u16 Bs[BN * BK];

    const int tid  = threadIdx.x;
    const int lane = tid & 63;
    const int wave = tid >> 6;
    const int wm = wave / WC, wn = wave % WC;

    const int m0 = blockIdx.y * BM;
    const int n0 = blockIdx.x * BN;
    const int Kchunk = K / gridDim.z;
    const int kbeg = blockIdx.z * Kchunk;
    const int kend = kbeg + Kchunk;

    f32x4 acc[MT][NT];
#pragma unroll
    for (int mi = 0; mi < MT; mi++)
#pragma unroll
        for (int ni = 0; ni < NT; ni++)
            acc[mi][ni] = (f32x4){0.f, 0.f, 0.f, 0.f};

    const int q = lane >> 4;               // k-quad this lane consumes
    const int arow = wm * MT * 16 + (lane & 15);
    const int brow = wn * NT * 16 + (lane & 15);

    constexpr int CHA = BM * 4;            // 16B chunks in A tile
    constexpr int CHB = BN * 4;

    for (int k0 = kbeg; k0 < kend; k0 += BK) {
        __syncthreads();
        // async stage A tile: chunk c holds global quad (c&3)^((row>>1)&3)
#pragma unroll
        for (int it = 0; it < (CHA + 255) / 256; it++) {
            const int c = it * 256 + tid;
            if (CHA % 256 == 0 || c < CHA) {
                const int row = c >> 2, kc = SWZ(row, c & 3);
                const u16* gp = &A[(size_t)(m0 + row) * K + k0 + kc * 8];
                __builtin_amdgcn_global_load_lds(
                    (const __attribute__((address_space(1))) void*)gp,
                    (__attribute__((address_space(3))) void*)&As[c * 8], 16, 0, 0);
            }
        }
#pragma unroll
        for (int it = 0; it < (CHB + 255) / 256; it++) {
            const int c = it * 256 + tid;
            if (CHB % 256 == 0 || c < CHB) {
                const int row = c >> 2, kc = SWZ(row, c & 3);
                const u16* gp = &Bt[(size_t)(n0 + row) * K + k0 + kc * 8];
                __builtin_amdgcn_global_load_lds(
                    (const __attribute__((address_space(1))) void*)gp,
                    (__attribute__((address_space(3))) void*)&Bs[c * 8], 16, 0, 0);
            }
        }
        __syncthreads();

        bf16x8 af[MT], bfr[NT];
#pragma unroll
        for (int mi = 0; mi < MT; mi++) {
            const int row = arow + mi * 16;
            af[mi] = *reinterpret_cast<const bf16x8*>(&As[row * BK + SWZ(row, q) * 8]);
        }
#pragma unroll
        for (int ni = 0; ni < NT; ni++) {
            const int row = brow + ni * 16;
            bfr[ni] = *reinterpret_cast<const bf16x8*>(&Bs[row * BK + SWZ(row, q) * 8]);
        }
#pragma unroll
        for (int mi = 0; mi < MT; mi++)
#pragma unroll
            for (int ni = 0; ni < NT; ni++)
                acc[mi][ni] = __builtin_amdgcn_mfma_f32_16x16x32_bf16(
                    af[mi], bfr[ni], acc[mi][ni], 0, 0, 0);
    }

    const int rb = m0 + wm * MT * 16 + ((lane >> 4) << 2);
    const int cb = n0 + wn * NT * 16 + (lane & 15);
#pragma unroll
    for (int mi = 0; mi < MT; mi++) {
#pragma unroll
        for (int ni = 0; ni < NT; ni++) {
            const int col = cb + ni * 16;
#pragma unroll
            for (int r = 0; r < 4; r++) {
                const int row = rb + mi * 16 + r;
                const float v = acc[mi][ni][r];
                if constexpr (MODE == 0) {
                    ((u16*)C)[(size_t)row * N + col] = f2bf(v);
                } else if constexpr (MODE == 5) {
                    ((float*)C)[((size_t)blockIdx.z * M + row) * N + col] = v;
                }
            }
        }
    }
}

// ---------------- reduce split-K partials -> x_dbl fp32 + dtin bf16 ---------
__global__ void reduce_xdbl(const float* __restrict__ part,
                            float* __restrict__ x_dbl, u16* __restrict__ dtin) {
    const int idx = blockIdx.x * 256 + threadIdx.x;   // 2048*160
    const int row = idx / 160, col = idx - row * 160;
    float s = 0.f;
#pragma unroll
    for (int z = 0; z < 8; z++) s += part[(size_t)z * (2048 * 160) + idx];
    x_dbl[idx] = s;
    if (col < 128) dtin[row * 128 + col] = f2bf(s);
}

// ---------------- dedicated dt GEMM: dt = softplus(dtin @ W_dtT^T + b) ------
// M=2048, N=4096, K=128 (whole K staged once). 64x64 tile, 2048 blocks.
// Epilogue: acc -> LDS fp32 [64][68] -> float4 coalesced global stores.
__global__ __launch_bounds__(256) void dt_gemm(
    const u16* __restrict__ A,      // dtin  [2048 x 128] bf16
    const u16* __restrict__ Bt,     // W_dtT [4096 x 128] bf16
    float* __restrict__ C,          // dtv   [2048 x 4096] fp32
    const u16* __restrict__ bias)   // b_dt  [4096] bf16
{
    __shared__ ulong4 smem_raw[2048];            // 32 KB
    u16* As = (u16*)smem_raw;                    // [64][128] swizzled bf16
    u16* Bs = As + 64 * 128;                     // [64][128] swizzled bf16
    float* Cs = (float*)smem_raw;                // [64][68] fp32 (aliases As/Bs)

    const int tid  = threadIdx.x;
    const int lane = tid & 63;
    const int wave = tid >> 6;
    const int n0 = blockIdx.x * 64;
    const int m0 = blockIdx.y * 64;

    // stage A and B tiles: 64 rows x 16 chunks (16 B) each, 4 iters x 256 thr.
#pragma unroll
    for (int it = 0; it < 4; it++) {
        const int c = it * 256 + tid;
        const int row = c >> 4, cc = (c & 15) ^ (row & 7);
        const u16* gp = &A[(size_t)(m0 + row) * 128 + cc * 8];
        __builtin_amdgcn_global_load_lds(
            (const __attribute__((address_space(1))) void*)gp,
            (__attribute__((address_space(3))) void*)&As[c * 8], 16, 0, 0);
    }
#pragma unroll
    for (int it = 0; it < 4; it++) {
        const int c = it * 256 + tid;
        const int row = c >> 4, cc = (c & 15) ^ (row & 7);
        const u16* gp = &Bt[(size_t)(n0 + row) * 128 + cc * 8];
        __builtin_amdgcn_global_load_lds(
            (const __attribute__((address_space(1))) void*)gp,
            (__attribute__((address_space(3))) void*)&Bs[c * 8], 16, 0, 0);
    }
    __syncthreads();

    // wave w owns rows m0 + w*16 .. +15, all 64 cols of the tile.
    const int q  = lane >> 4;                 // k-quad this lane consumes
    const int ar = wave * 16 + (lane & 15);   // A row within tile
    f32x4 acc[4];
#pragma unroll
    for (int ni = 0; ni < 4; ni++) acc[ni] = (f32x4){0.f, 0.f, 0.f, 0.f};

#pragma unroll
    for (int kk = 0; kk < 4; kk++) {          // 4 k-slabs of 32
        const int cA = kk * 4 + q;            // 16B chunk index within row
        const bf16x8 af = *reinterpret_cast<const bf16x8*>(
            &As[(ar * 16 + (cA ^ (ar & 7))) * 8]);
#pragma unroll
        for (int ni = 0; ni < 4; ni++) {
            const int br = ni * 16 + (lane & 15);
            const bf16x8 bfr = *reinterpret_cast<const bf16x8*>(
                &Bs[(br * 16 + (cA ^ (br & 7))) * 8]);
            acc[ni] = __builtin_amdgcn_mfma_f32_16x16x32_bf16(af, bfr, acc[ni], 0, 0, 0);
        }
    }
    __syncthreads();   // all As/Bs reads done before Cs overwrites them

    // fragment -> LDS fp32 tile (stride 68 breaks the 256B bank aliasing)
#pragma unroll
    for (int ni = 0; ni < 4; ni++) {
        const int col = ni * 16 + (lane & 15);
#pragma unroll
        for (int r = 0; r < 4; r++) {
            const int rowl = wave * 16 + q * 4 + r;
            Cs[rowl * 68 + col] = acc[ni][r];
        }
    }
    __syncthreads();

    // LDS -> global: 4 passes x float4 per thread; bias + softplus fused.
#pragma unroll
    for (int p = 0; p < 4; p++) {
        const int rowl = p * 16 + (tid >> 4);
        const int c0 = (tid & 15) * 4;
        float4 v = *reinterpret_cast<const float4*>(&Cs[rowl * 68 + c0]);
        float* vp = reinterpret_cast<float*>(&v);
#pragma unroll
        for (int j = 0; j < 4; j++) {
            const float x = vp[j] + bf2f(bias[n0 + c0 + j]);
            // softplus(x) = max(x,0) + log1p(exp(-|x|)); fast hw exp/log
            vp[j] = fmaxf(x, 0.f) + __logf(1.f + __expf(-fabsf(x)));
        }
        *reinterpret_cast<float4*>(&C[(size_t)(m0 + rowl) * 4096 + n0 + c0]) = v;
    }
}

// ---------------- depthwise conv3 + bias + silu (8 ch/thread) ---------------
__global__ void conv_silu(const u16* __restrict__ xz, const u16* __restrict__ conv_w,
                          const u16* __restrict__ conv_b, u16* __restrict__ xc) {
    const int idx = blockIdx.x * 256 + threadIdx.x;    // 2048*512 threads
    const int row = idx >> 9, c0 = (idx & 511) * 8;
    const int l = row & 1023;

    u16 wcat[24];
    *(u16x8*)&wcat[0]  = *(const u16x8*)&conv_w[c0 * 3];
    *(u16x8*)&wcat[8]  = *(const u16x8*)&conv_w[c0 * 3 + 8];
    *(u16x8*)&wcat[16] = *(const u16x8*)&conv_w[c0 * 3 + 16];
    const u16x8 bv = *(const u16x8*)&conv_b[c0];
    const u16x8 x0 = *(const u16x8*)&xz[(size_t)row * 8192 + c0];
    u16x8 xm = {}, xp = {};
    if (l > 0)    xm = *(const u16x8*)&xz[(size_t)(row - 1) * 8192 + c0];
    if (l < 1023) xp = *(const u16x8*)&xz[(size_t)(row + 1) * 8192 + c0];

    u16x8 out;
#pragma unroll
    for (int i = 0; i < 8; i++) {
        float v = bf2f(wcat[3 * i]) * bf2f(xm[i])
                + bf2f(wcat[3 * i + 1]) * bf2f(x0[i])
                + bf2f(wcat[3 * i + 2]) * bf2f(xp[i])
                + bf2f(bv[i]);
        v = v / (1.f + __expf(-v));
        out[i] = f2bf(v);
    }
    *(u16x8*)&xc[(size_t)row * 4096 + c0] = out;
}

// ---------------- S1: per-chunk local scan (h_in = 0), lane = channel -------
// grid (NCHUNK, 16, 2), 256 threads: lane owns all 16 states of one channel.
__global__ __launch_bounds__(256) void scan_p1(
    const float* __restrict__ dt, const u16* __restrict__ xc,
    const float* __restrict__ x_dbl, const u16* __restrict__ A_log,
    float* __restrict__ Parr, u16* __restrict__ xzbase)
{
    __shared__ float Bsm[CLEN][16];
    const int tid = threadIdx.x;
    const int nc = blockIdx.x, cg = blockIdx.y, b = blockIdx.z;
    const int ch = cg * 256 + tid;
    const size_t row0 = (size_t)b * 1024 + nc * CLEN;

    {   // stage B[t][s]: 64 rows x 16 floats; 256 threads x 1 float4
        const int t = tid >> 2, q = tid & 3;
        const float4 v = *(const float4*)&x_dbl[(row0 + t) * 160 + 128 + q * 4];
        *(float4*)&Bsm[t][q * 4] = v;
    }
    __syncthreads();

    float A_s[16], h[16];
#pragma unroll
    for (int s = 0; s < 16; s++) {
        A_s[s] = -__expf(bf2f(A_log[ch * 16 + s]));
        h[s] = 0.f;
    }
    float Sdt = 0.f;

    float dt_v = dt[row0 * 4096 + ch];
    float u_v  = bf2f(xc[row0 * 4096 + ch]);
    for (int t = 0; t < CLEN; t++) {
        const int tn = (t + 1 < CLEN) ? t + 1 : t;
        const float dt_n = dt[(row0 + tn) * 4096 + ch];
        const float u_n  = bf2f(xc[(row0 + tn) * 4096 + ch]);
        const float dtu = dt_v * u_v;
        Sdt += dt_v;
        const f32x4* Brow = (const f32x4*)&Bsm[t][0];
        const f32x4 B0 = Brow[0], B1 = Brow[1], B2 = Brow[2], B3 = Brow[3];
#pragma unroll
        for (int s = 0; s < 16; s++) {
            const float Bs_ = (s < 4 ? B0[s & 3] : s < 8 ? B1[s & 3] : s < 12 ? B2[s & 3] : B3[s & 3]);
            const float dA = __expf(dt_v * A_s[s]);
            h[s] = dA * h[s] + dtu * Bs_;
        }
        dt_v = dt_n; u_v = u_n;
    }
    const int i0 = (((b * NCHUNK + nc) * 4096) + ch) * 16;
    float* pp = &Parr[i0];
    float* hp = hloc_ptr(xzbase, i0);
#pragma unroll
    for (int s4 = 0; s4 < 4; s4++) {
        float4 pq, hq;
        pq.x = __expf(A_s[4 * s4 + 0] * Sdt);
        pq.y = __expf(A_s[4 * s4 + 1] * Sdt);
        pq.z = __expf(A_s[4 * s4 + 2] * Sdt);
        pq.w = __expf(A_s[4 * s4 + 3] * Sdt);
        hq.x = h[4 * s4 + 0]; hq.y = h[4 * s4 + 1];
        hq.z = h[4 * s4 + 2]; hq.w = h[4 * s4 + 3];
        *(float4*)&pp[4 * s4] = pq;
        *(float4*)&hp[4 * s4] = hq;
    }
}

// ---------------- S2: combine chunk summaries -> h_in -----------------------
__global__ __launch_bounds__(256) void scan_p2(
    const float* __restrict__ Parr, u16* __restrict__ xzbase)
{
    const int tid = threadIdx.x;
    const int lane = tid & 63, wave = tid >> 6;
    const int blk = blockIdx.x;
    const int b = blk >> 8, cg = blk & 255;
    const int c_local = lane & 3, s = lane >> 2;
    const int ch = cg * 16 + wave * 4 + c_local;

    float Pv[NCHUNK], hl[NCHUNK];
#pragma unroll
    for (int c = 0; c < NCHUNK; c++) {
        const int i = (((b * NCHUNK + c) * 4096) + ch) * 16 + s;
        Pv[c] = Parr[i];
        hl[c] = *hloc_ptr(xzbase, i);
    }
    float hin = 0.f;
#pragma unroll
    for (int c = 0; c < NCHUNK; c++) {
        const int i = (((b * NCHUNK + c) * 4096) + ch) * 16 + s;
        *hin_ptr(xzbase, i) = hin;
        hin = Pv[c] * hin + hl[c];
    }
}

// ---------------- S3: rescan with h_in; fused gate; lane = channel ----------
__global__ __launch_bounds__(256) void scan_p3(
    const float* __restrict__ dt, const u16* __restrict__ xc,
    const float* __restrict__ x_dbl, const u16* __restrict__ xz,
    const u16* __restrict__ A_log, const u16* __restrict__ Dp,
    u16* __restrict__ yg, u16* __restrict__ xzbase)
{
    __shared__ float BCs[CLEN][32];   // [t][0..15]=B, [t][16..31]=C
    const int tid = threadIdx.x;
    const int nc = blockIdx.x, cg = blockIdx.y, b = blockIdx.z;
    const int ch = cg * 256 + tid;
    const size_t row0 = (size_t)b * 1024 + nc * CLEN;

#pragma unroll
    for (int it = 0; it < 2; it++) {   // 64 rows x 32 floats; 512 float4
        const int c = it * 256 + tid;
        const int t = c >> 3, q = c & 7;
        const float4 v = *(const float4*)&x_dbl[(row0 + t) * 160 + 128 + q * 4];
        *(float4*)&BCs[t][q * 4] = v;
    }
    __syncthreads();

    float A_s[16], h[16];
    const int i0 = (((b * NCHUNK + nc) * 4096) + ch) * 16;
    {
        const float* hp = hin_ptr(xzbase, i0);
#pragma unroll
        for (int s4 = 0; s4 < 4; s4++) {
            const float4 hq = *(const float4*)&hp[4 * s4];
            h[4 * s4 + 0] = hq.x; h[4 * s4 + 1] = hq.y;
            h[4 * s4 + 2] = hq.z; h[4 * s4 + 3] = hq.w;
        }
    }
#pragma unroll
    for (int s = 0; s < 16; s++)
        A_s[s] = -__expf(bf2f(A_log[ch * 16 + s]));
    const float D_ch = bf2f(Dp[ch]);

    float dt_v = dt[row0 * 4096 + ch];
    float u_v  = bf2f(xc[row0 * 4096 + ch]);
    float z_v  = bf2f(xz[row0 * 8192 + 4096 + ch]);
    for (int t = 0; t < CLEN; t++) {
        const int tn = (t + 1 < CLEN) ? t + 1 : t;
        const size_t rn = row0 + tn;
        const float dt_n = dt[rn * 4096 + ch];
        const float u_n  = bf2f(xc[rn * 4096 + ch]);
        const float z_n  = bf2f(xz[rn * 8192 + 4096 + ch]);
        const float dtu = dt_v * u_v;

        const f32x4* Row = (const f32x4*)&BCs[t][0];
        const f32x4 B0 = Row[0], B1 = Row[1], B2 = Row[2], B3 = Row[3];
        const f32x4 C0 = Row[4], C1 = Row[5], C2 = Row[6], C3 = Row[7];

        float y0 = 0.f, y1 = 0.f, y2 = 0.f, y3 = 0.f;
#pragma unroll
        for (int s = 0; s < 16; s++) {
            const float Bs_ = (s < 4 ? B0[s & 3] : s < 8 ? B1[s & 3] : s < 12 ? B2[s & 3] : B3[s & 3]);
            const float Cs_ = (s < 4 ? C0[s & 3] : s < 8 ? C1[s & 3] : s < 12 ? C2[s & 3] : C3[s & 3]);
            const float dA = __expf(dt_v * A_s[s]);
            h[s] = dA * h[s] + dtu * Bs_;
            const float hc = h[s] * Cs_;
            if ((s & 3) == 0) y0 += hc; else if ((s & 3) == 1) y1 += hc;
            else if ((s & 3) == 2) y2 += hc; else y3 += hc;
        }
        const float y = (y0 + y1) + (y2 + y3);
        const float silu_z = z_v / (1.f + __expf(-z_v));
        yg[(row0 + t) * 4096 + ch] = f2bf((y + u_v * D_ch) * silu_z);
        dt_v = dt_n; u_v = u_n; z_v = z_n;
    }
}

extern "C" void kernel_launch(void* const* d_in, const int* in_sizes, int n_in,
                              void* d_out, int out_size, void* d_ws, size_t ws_size,
                              hipStream_t stream)
{
    const void* x_raw      = d_in[0];   // (2,1024,2048)
    const void* W_in_raw   = d_in[1];   // (2048,8192)
    const void* conv_w_raw = d_in[2];   // (4096,1,3)
    const void* conv_b_raw = d_in[3];   // (4096)
    const void* W_x_raw    = d_in[4];   // (4096,160)
    const void* W_dt_raw   = d_in[5];   // (128,4096)
    const void* b_dt_raw   = d_in[6];   // (4096)
    const void* A_log_raw  = d_in[7];   // (4096,16)
    const void* D_raw      = d_in[8];   // (4096)
    const void* W_out_raw  = d_in[9];   // (4096,2048)

    char* ws = (char*)d_ws;
    size_t off = 0;
    auto alloc = [&](size_t bytes) { char* p = ws + off; off += (bytes + 255) & ~(size_t)255; return p; };
    int*   flag   = (int*)  alloc(4);
    u16*   W_inT  = (u16*)  alloc(8192ULL * 2048 * 2);   // 32 MB (aliased by dt fp32 after K1, then K6 partials)
    u16*   W_outT = (u16*)  alloc(2048ULL * 4096 * 2);   // 16 MB
    u16*   W_dtT  = (u16*)  alloc(4096ULL * 128 * 2);    // 1 MB
    u16*   W_xT   = (u16*)  alloc(160ULL * 4096 * 2);    // 1.25 MB
    u16*   xz     = (u16*)  alloc(2048ULL * 8192 * 2);   // 32 MB (xp half reused as h_loc/h_in)
    u16*   xc     = (u16*)  alloc(2048ULL * 4096 * 2);   // 16 MB
    float* x_dbl  = (float*)alloc(2048ULL * 160 * 4);    // 1.25 MB
    u16*   dtin   = (u16*)  alloc(2048ULL * 128 * 2);    // 0.5 MB
    u16*   yg     = (u16*)  alloc(2048ULL * 4096 * 2);   // 16 MB
    u16*   xcan   = (u16*)  alloc(2048ULL * 2048 * 2);   // 8 MB (reused as Parr fp32)
    float* xdblp  = (float*)alloc(8ULL * 2048 * 160 * 4);// 10.5 MB split-K partials
    u16*   cw_c   = (u16*)  alloc(12288 * 2);
    u16*   cb_c   = (u16*)  alloc(4096 * 2);
    u16*   bdt_c  = (u16*)  alloc(4096 * 2);
    u16*   Alog_c = (u16*)  alloc(65536 * 2);
    u16*   D_c    = (u16*)  alloc(4096 * 2);
    float* dtv    = (float*)W_inT;   // alias: W_inT dead after K1 (32 MB exact)
    float* Parr   = (float*)xcan;    // alias: xcan dead after K1 (8 MB exact)
    float* outp   = (float*)W_inT;   // alias: dtv dead after scan_p3 (33.5 MB exact)

    // D) dtype flag, fused canonicalize
    detect_dtype<<<1, 256, 0, stream>>>((const u16*)x_raw, flag);
    cvt_fused<<<2048 + 6 + 2 + 2 + 32 + 2, 256, 0, stream>>>(
        x_raw, xcan, conv_w_raw, cw_c, conv_b_raw, cb_c, b_dt_raw, bdt_c,
        A_log_raw, Alog_c, D_raw, D_c, flag);

    // T) fused transposes (64x32 tiles, vec reads, u32 writes)
    transpose_fused<<<8192 + 4096 + 256 + 320, dim3(32, 8), 0, stream>>>(
        W_in_raw, W_inT, W_out_raw, W_outT, W_dt_raw, W_dtT, W_x_raw, W_xT, flag);

    // K1: xz = x @ W_in   (M=2048, N=8192, K=2048), 256^2 ring-4 af-prefetch
    (void)hipFuncSetAttribute(
        reinterpret_cast<const void*>(&gemm_ring<256, 256, 2, 4, 0>),
        hipFuncAttributeMaxDynamicSharedMemorySize, 131072);
    gemm_ring<256, 256, 2, 4, 0><<<dim3(8192 / 256, 2048 / 256, 1), 512, 131072, stream>>>(
        xcan, W_inT, xz, nullptr, 2048, 8192, 2048);

    // K2: conv + bias + silu (8 ch/thread)
    conv_silu<<<(2048 * 512) / 256, 256, 0, stream>>>(xz, cw_c, cb_c, xc);

    // K3: x_dbl partials = xc @ W_x   (split-K=8, plain fp32 stores)
    gemm_bt<64, 160, 32, 4, 1, 1, 10, 5>
        <<<dim3(1, 2048 / 64, 8), 256, 0, stream>>>(xc, W_xT, xdblp, nullptr, nullptr, 2048, 160, 4096);

    // R) reduce partials -> x_dbl fp32 + dtin bf16
    reduce_xdbl<<<(2048 * 160) / 256, 256, 0, stream>>>(xdblp, x_dbl, dtin);

    // K4: dt = softplus(dtin @ W_dt + b_dt)   (fp32 out, dedicated kernel)
    dt_gemm<<<dim3(4096 / 64, 2048 / 64), 256, 0, stream>>>(dtin, W_dtT, dtv, bdt_c);

    // S1/S2/S3: chunked selective scan (lane=channel) with fused gating
    scan_p1<<<dim3(NCHUNK, 16, 2), 256, 0, stream>>>(dtv, xc, x_dbl, Alog_c, Parr, xz);
    scan_p2<<<512, 256, 0, stream>>>(Parr, xz);
    scan_p3<<<dim3(NCHUNK, 16, 2), 256, 0, stream>>>(dtv, xc, x_dbl, xz, Alog_c, D_c, yg, xz);

    // K6: out = yg @ W_out (M=2048, N=2048, K=4096), split-K=2 ring + reduce
    (void)hipFuncSetAttribute(
        reinterpret_cast<const void*>(&gemm_ring<128, 128, 2, 2, 2>),
        hipFuncAttributeMaxDynamicSharedMemorySize, 65536);
    gemm_ring<128, 128, 2, 2, 2><<<dim3(2048 / 128, 2048 / 128, 2), 256, 65536, stream>>>(
        yg, W_outT, outp, nullptr, 2048, 2048, 4096);
    reduce_out<<<(2048 * 2048 / 4) / 256, 256, 0, stream>>>(outp, d_out, flag);
}